// Round 5
// baseline (450.616 us; speedup 1.0000x reference)
//
#include <hip/hip_runtime.h>
#include <hip/hip_bf16.h>

// VolatilityModulatedAttention: B=2, S=4096, H=512, NH=8, HD=64
// Round 11: prep fused into attn behind a per-bh 32-block counter barrier
// (deadlock-free under in-order dispatch; ms-scale valve that PROCEEDS on
// break -> wrong-answer diagnostic, never a hang). flags zeroed by a tiny
// zero_kernel (no hipMemsetAsync in capture). Grid-wide barrier abandoned
// (R10 lesson: full-grid residency is not guaranteed -> container kill).
// Hot-loop P-pack switched to 1-op bit-truncation (bias cancels in O/L).
// proj unchanged from validated R9.

#define S_LEN 4096
#define HD 64
#define HTOT 512

typedef __attribute__((ext_vector_type(8))) short short8;
typedef __attribute__((ext_vector_type(4))) float floatx4;

#if __has_builtin(__builtin_amdgcn_exp2f)
#define EXP2F(x) __builtin_amdgcn_exp2f(x)
#else
#define EXP2F(x) exp2f(x)
#endif

__device__ __forceinline__ unsigned pack_bf16(float a, float b) {
    unsigned ua = __builtin_bit_cast(unsigned, a) + 0x8000u;
    unsigned ub = __builtin_bit_cast(unsigned, b) + 0x8000u;
    return __builtin_amdgcn_perm(ub, ua, 0x07060302u);
}

// truncation pack (no rounding adds): lo=trunc_bf16(a), hi=trunc_bf16(b).
// Valid for P only: O and L consume identical stored P, so the uniform
// truncation bias cancels exactly in O/L.
__device__ __forceinline__ unsigned pack_trunc(float a, float b) {
    return __builtin_amdgcn_perm(__builtin_bit_cast(unsigned, b),
                                 __builtin_bit_cast(unsigned, a), 0x07060302u);
}

__device__ __forceinline__ unsigned short f2bf(float x) {
    unsigned u = __builtin_bit_cast(unsigned, x) + 0x8000u;
    return (unsigned short)(u >> 16);
}

__device__ __forceinline__ void async16(const unsigned short* g, unsigned short* l) {
    __builtin_amdgcn_global_load_lds(
        (const __attribute__((address_space(1))) unsigned int*)g,
        (__attribute__((address_space(3))) unsigned int*)l, 16, 0, 0);
}

// Arrive-and-wait barrier over 32 blocks (one bh group). Monotonic epochs
// (flags zeroed per launch by zero_kernel). Valve: ~30ms then PROCEED.
__device__ __forceinline__ void sync_bh(unsigned* c) {
    __threadfence();
    __syncthreads();
    if (threadIdx.x == 0) {
        unsigned v = __hip_atomic_fetch_add(c, 1u, __ATOMIC_ACQ_REL,
                                            __HIP_MEMORY_SCOPE_AGENT);
        unsigned target = ((v >> 5) + 1u) << 5;
        int guard = 0;
        while (__hip_atomic_load(c, __ATOMIC_ACQUIRE,
                                 __HIP_MEMORY_SCOPE_AGENT) < target) {
            __builtin_amdgcn_s_sleep(8);
            if (++guard > (1 << 17)) break;   // ms-scale valve: terminate, don't hang
        }
    }
    __syncthreads();
    __threadfence();
}

__global__ void zero_kernel(unsigned* __restrict__ flags) {
    if (threadIdx.x < 16) flags[threadIdx.x] = 0;
}

// ---------------------------------------------------------------------------
// Fused prep + flash attention. Grid 512 x 512thr = (b*8+h)*32 + qt.
// Phase 1: this block's slice of K fp32->bf16, V transpose (2 tiles), W
// (bid<64). Per-bh barrier. Phase 2: R9-validated attn body (K-split via
// wave-groups, P in registers, f32 LDS combine epilogue, direct ctx write).
// ---------------------------------------------------------------------------
__global__ __launch_bounds__(512, 4) void attn_kernel(
    const float* __restrict__ Q, const float* __restrict__ K,
    const float* __restrict__ V, const float* __restrict__ W,
    const float* __restrict__ risk_sigma, const float* __restrict__ risk_lambda,
    unsigned short* __restrict__ K16, unsigned short* __restrict__ Vt,
    unsigned short* __restrict__ W16, unsigned* __restrict__ flags,
    unsigned short* __restrict__ ctx)
{
    __shared__ unsigned short SH[32768];   // 64 KiB, reused across phases

    const int tid = threadIdx.x;
    const int bid = blockIdx.x;            // (b*8+h)*32 + qt
    const int qt  = bid & 31;
    const int bh  = bid >> 5;
    const int b   = bh >> 3;
    const int h   = bh & 7;
    const int qbase = qt * 128;

    // ===================== PHASE 1: PREP =====================
    {   // K fp32->bf16, own 128-row stripe of this (b,h)'s slice
        const int u   = qt * 512 + tid;            // 0..16383 within bh
        const int row = u >> 2;
        const int c16 = (u & 3) * 16;
        const size_t off = ((size_t)b * S_LEN + row) * HTOT + h * HD + c16;
        float4 a0 = *(const float4*)(K + off);
        float4 a1 = *(const float4*)(K + off + 4);
        float4 a2 = *(const float4*)(K + off + 8);
        float4 a3 = *(const float4*)(K + off + 12);
        unsigned o0[4] = {pack_bf16(a0.x, a0.y), pack_bf16(a0.z, a0.w),
                          pack_bf16(a1.x, a1.y), pack_bf16(a1.z, a1.w)};
        unsigned o1[4] = {pack_bf16(a2.x, a2.y), pack_bf16(a2.z, a2.w),
                          pack_bf16(a3.x, a3.y), pack_bf16(a3.z, a3.w)};
        *(short8*)(K16 + off)     = *(short8*)o0;
        *(short8*)(K16 + off + 8) = *(short8*)o1;
    }
    {   // V per-head transpose: two 64x64 tiles (tid split into 256-thread halves)
        const int vh = tid >> 8;                   // 0/1
        const int t2 = tid & 255;
        const int st = qt * 2 + vh;
        unsigned short* T = SH + vh * 4224;        // 64*66 shorts each
        const float* src = V + ((size_t)b * S_LEN + st * 64) * HTOT + h * HD;
        for (int i = 0; i < 4; i++) {
            int idx = t2 + i * 256;
            int s = idx >> 4, c4 = idx & 15;
            float4 v = *(const float4*)(src + (size_t)s * HTOT + c4 * 4);
            T[(c4 * 4 + 0) * 66 + s] = f2bf(v.x);
            T[(c4 * 4 + 1) * 66 + s] = f2bf(v.y);
            T[(c4 * 4 + 2) * 66 + s] = f2bf(v.z);
            T[(c4 * 4 + 3) * 66 + s] = f2bf(v.w);
        }
        __syncthreads();
        unsigned short* dst = Vt + ((size_t)bh * 64) * S_LEN + st * 64;
        for (int i = 0; i < 2; i++) {
            int idx = t2 + i * 256;
            int d = idx >> 3, c8 = idx & 7;
            uint2 lo = *(const uint2*)&T[d * 66 + c8 * 8];
            uint2 hi = *(const uint2*)&T[d * 66 + c8 * 8 + 4];
            unsigned o[4] = {lo.x, lo.y, hi.x, hi.y};
            *(short8*)(dst + (size_t)d * S_LEN + c8 * 8) = *(short8*)o;
        }
    }
    if (bid < 64) {   // W fp32->bf16 (for proj, no barrier needed: later kernel)
        size_t i = ((size_t)bid * 512 + tid) * 8;
        float4 a = *(const float4*)(W + i);
        float4 c = *(const float4*)(W + i + 4);
        unsigned o[4] = {pack_bf16(a.x, a.y), pack_bf16(a.z, a.w),
                         pack_bf16(c.x, c.y), pack_bf16(c.z, c.w)};
        *(short8*)(W16 + i) = *(short8*)o;
    }

    sync_bh(&flags[bh]);    // this (b,h)'s 32 blocks: K16/Vt slice ready

    // ===================== PHASE 2: ATTN (R9 verbatim + P-trunc) ============
    {
        const int wave = tid >> 6;
        const int grp  = wave >> 2;            // K-split half
        const int wv   = wave & 3;             // wave within group
        const int lane = tid & 63;
        const int quad = lane >> 4;
        const int ln   = lane & 15;
        const int sw   = ln & 7;

        float sig = risk_sigma[b];
        sig = fminf(fmaxf(sig, 0.001f), 0.2f);
        const float sn   = (sig - 0.001f) * (1.0f / 0.199f);
        const float coef = risk_lambda[0] * 0.1f * sn;
        const float nc2 = -coef * (1.0f / 4096.0f) * (1.0f / 4096.0f) * 1.4426950408889634f;
        const float qscale = 0.125f * 1.4426950408889634f;

        const float* Qb = Q + (size_t)b * S_LEN * HTOT + (size_t)h * HD;
        const unsigned short* Kb = K16 + (size_t)b * S_LEN * HTOT + (size_t)h * HD;
        const unsigned short* Vb = Vt + ((size_t)(b * 8 + h) * 64) * S_LEN;

        const int rl  = lane >> 3;
        const int c8g = ((lane & 7) ^ rl) << 3;
        const int ksrow = ((wv & 1) << 4) | (((rl >> 2) & 1) << 3)
                        | ((wv >> 1) << 2) | (rl & 3);

        auto dma = [&](int buf, int kb) {
            unsigned short* base = SH + (grp * 2 + buf) * 8192;  // K +0, V +4096
            const unsigned short* gk = Kb + (size_t)(kb + ksrow) * HTOT + c8g;
            const unsigned short* gv = Vb + (size_t)(wv * 8 + rl) * S_LEN + kb + c8g;
            async16(gk,              base + wv * 512 + lane * 8);
            async16(gk + 32 * HTOT,  base + (wv + 4) * 512 + lane * 8);
            async16(gv,              base + 4096 + wv * 512 + lane * 8);
            async16(gv + 32 * S_LEN, base + 4096 + (wv + 4) * 512 + lane * 8);
        };

        const int kb0 = grp * 2048;
        dma(0, kb0);

        short8 qf[2][2];
        {
            const float* qp0 = Qb + (size_t)(qbase + wv * 32 + ln) * HTOT + quad * 8;
            #pragma unroll
            for (int nt = 0; nt < 2; nt++) {
                const float* qp = qp0 + (size_t)(nt * 16) * HTOT;
                #pragma unroll
                for (int hf = 0; hf < 2; hf++) {
                    float4 x = *(const float4*)(qp + hf * 32);
                    float4 y = *(const float4*)(qp + hf * 32 + 4);
                    unsigned o[4] = {pack_bf16(x.x * qscale, x.y * qscale),
                                     pack_bf16(x.z * qscale, x.w * qscale),
                                     pack_bf16(y.x * qscale, y.y * qscale),
                                     pack_bf16(y.z * qscale, y.w * qscale)};
                    qf[nt][hf] = *(short8*)o;
                }
            }
        }
        __syncthreads();   // drains dma(0)

        const short sone = (short)0x3F80;
        const short8 ones = {sone, sone, sone, sone, sone, sone, sone, sone};

        floatx4 Oacc[2][4], Lacc[2];
        #pragma unroll
        for (int nt = 0; nt < 2; nt++) {
            Lacc[nt] = (floatx4){0.f, 0.f, 0.f, 0.f};
            #pragma unroll
            for (int dt = 0; dt < 4; dt++) Oacc[nt][dt] = (floatx4){0.f, 0.f, 0.f, 0.f};
        }

        const int qa = qbase + wv * 32;
        const float quad8f = (float)(quad * 8);

        for (int kt = 0; kt < 32; ++kt) {
            const int kbase = kb0 + kt * 64;
            const int cur = kt & 1;
            if (kt < 31) dma(1 - cur, kbase + 64);
            const unsigned short* Kc = SH + (grp * 2 + cur) * 8192;
            const unsigned short* Vc = Kc + 4096;

            const float dqq = (float)(qa + ln - kbase) - quad8f;
            unsigned pw[2][2][4];   // [nt][part][word] — PV A-fragments

            #pragma unroll
            for (int jt = 0; jt < 4; jt++) {
                const int krow = (jt * 16 + ln) * 64;
                short8 ak0 = *(const short8*)&Kc[krow + ((quad ^ sw) << 3)];
                short8 ak1 = *(const short8*)&Kc[krow + (((quad + 4) ^ sw) << 3)];
                const float jtoff = (float)((jt >> 1) * 32 + (jt & 1) * 4);
                #pragma unroll
                for (int nt = 0; nt < 2; nt++) {
                    float d = dqq + ((float)(nt * 16) - jtoff);
                    floatx4 rk;
                    #pragma unroll
                    for (int r = 0; r < 4; r++) {
                        rk[r] = (nc2 * d) * d;
                        d -= 1.0f;
                    }
                    floatx4 s = __builtin_amdgcn_mfma_f32_16x16x32_bf16(ak0, qf[nt][0], rk, 0, 0, 0);
                    s = __builtin_amdgcn_mfma_f32_16x16x32_bf16(ak1, qf[nt][1], s, 0, 0, 0);
                    float p0 = EXP2F(s[0]);
                    float p1 = EXP2F(s[1]);
                    float p2 = EXP2F(s[2]);
                    float p3 = EXP2F(s[3]);
                    pw[nt][jt >> 1][(jt & 1) * 2 + 0] = pack_trunc(p0, p1);
                    pw[nt][jt >> 1][(jt & 1) * 2 + 1] = pack_trunc(p2, p3);
                }
            }

            __builtin_amdgcn_s_setprio(1);
            #pragma unroll
            for (int dt = 0; dt < 4; dt++) {
                const int vrow = (dt * 16 + ln) * 64;
                short8 bv0 = *(const short8*)&Vc[vrow + ((quad ^ sw) << 3)];
                short8 bv1 = *(const short8*)&Vc[vrow + (((quad + 4) ^ sw) << 3)];
                #pragma unroll
                for (int nt = 0; nt < 2; nt++) {
                    short8 pa0 = *(const short8*)&pw[nt][0][0];
                    short8 pa1 = *(const short8*)&pw[nt][1][0];
                    Oacc[nt][dt] = __builtin_amdgcn_mfma_f32_16x16x32_bf16(pa0, bv0, Oacc[nt][dt], 0, 0, 0);
                    Oacc[nt][dt] = __builtin_amdgcn_mfma_f32_16x16x32_bf16(pa1, bv1, Oacc[nt][dt], 0, 0, 0);
                }
            }
            #pragma unroll
            for (int nt = 0; nt < 2; nt++) {
                short8 pa0 = *(const short8*)&pw[nt][0][0];
                short8 pa1 = *(const short8*)&pw[nt][1][0];
                Lacc[nt] = __builtin_amdgcn_mfma_f32_16x16x32_bf16(pa0, ones, Lacc[nt], 0, 0, 0);
                Lacc[nt] = __builtin_amdgcn_mfma_f32_16x16x32_bf16(pa1, ones, Lacc[nt], 0, 0, 0);
            }
            __builtin_amdgcn_s_setprio(0);
            __syncthreads();
        }

        // ---- epilogue: cross-group combine in LDS (f32), direct ctx write ----
        float* X   = (float*)SH;               // [128][68] f32
        float* Lsh = (float*)SH + 128 * 68;    // [2][128] f32

        if (ln == 0) {
            #pragma unroll
            for (int nt = 0; nt < 2; nt++)
                #pragma unroll
                for (int r = 0; r < 4; r++)
                    Lsh[grp * 128 + wv * 32 + nt * 16 + quad * 4 + r] = Lacc[nt][r];
        }
        if (grp == 0) {
            #pragma unroll
            for (int nt = 0; nt < 2; nt++)
                #pragma unroll
                for (int dt = 0; dt < 4; dt++)
                    #pragma unroll
                    for (int r = 0; r < 4; r++)
                        X[(wv * 32 + nt * 16 + quad * 4 + r) * 68 + dt * 16 + ln] = Oacc[nt][dt][r];
        }
        __syncthreads();
        if (grp == 1) {
            #pragma unroll
            for (int nt = 0; nt < 2; nt++) {
                float inv[4];
                #pragma unroll
                for (int r = 0; r < 4; r++) {
                    int row = wv * 32 + nt * 16 + quad * 4 + r;
                    inv[r] = 1.0f / (Lsh[row] + Lsh[128 + row]);
                }
                #pragma unroll
                for (int dt = 0; dt < 4; dt++)
                    #pragma unroll
                    for (int r = 0; r < 4; r++) {
                        int row = wv * 32 + nt * 16 + quad * 4 + r;
                        float* p = &X[row * 68 + dt * 16 + ln];
                        *p = (*p + Oacc[nt][dt][r]) * inv[r];
                    }
            }
        }
        __syncthreads();
        {
            const int q = tid >> 2;            // 128 rows, 4 threads/row
            const int c = tid & 3;             // 16-d chunk
            const float* xp = X + q * 68 + c * 16;
            float4 x0 = *(const float4*)(xp + 0);
            float4 x1 = *(const float4*)(xp + 4);
            float4 x2 = *(const float4*)(xp + 8);
            float4 x3 = *(const float4*)(xp + 12);
            unsigned o0[4] = {pack_bf16(x0.x, x0.y), pack_bf16(x0.z, x0.w),
                              pack_bf16(x1.x, x1.y), pack_bf16(x1.z, x1.w)};
            unsigned o1[4] = {pack_bf16(x2.x, x2.y), pack_bf16(x2.z, x2.w),
                              pack_bf16(x3.x, x3.y), pack_bf16(x3.z, x3.w)};
            unsigned short* cp = ctx + ((size_t)b * S_LEN + qbase + q) * HTOT + h * HD + c * 16;
            *(short8*)cp       = *(short8*)o0;
            *(short8*)(cp + 8) = *(short8*)o1;
        }
    }
}

// ---------------------------------------------------------------------------
// Projection GEMM, all-bf16, DMA double-buffered staging. (R9 verbatim)
// ---------------------------------------------------------------------------
__global__ __launch_bounds__(256) void proj_kernel(
    const unsigned short* __restrict__ A,   // ctx bf16 [8192 x 512]
    const unsigned short* __restrict__ W16, // [512 x 512] bf16
    const float* __restrict__ bias,
    float* __restrict__ out)
{
    __shared__ unsigned short Ash[2][64 * 32];
    __shared__ unsigned short Bsh[2][128 * 32];
    const int tid = threadIdx.x;
    const int wave = tid >> 6, lane = tid & 63, quad = lane >> 4, ln = lane & 15;
    const int wr = wave >> 1, wc = wave & 1;
    const int m0 = blockIdx.y * 64;
    const int nb = blockIdx.x * 128;

    const int arow = (wave * 64 + lane) >> 2;
    const int ac   = (wave * 64 + lane) & 3;
    const int acs  = (ac ^ ((arow >> 1) & 3)) << 3;
    const int wrow0 = (wave * 64 + lane) >> 2;
    const int wc0   = (wave * 64 + lane) & 3;
    const int wcs0  = (wc0 ^ ((wrow0 >> 1) & 3)) << 3;
    const int wrow1 = wrow0 + 64;
    const int wcs1  = (wc0 ^ ((wrow1 >> 1) & 3)) << 3;

    auto dma = [&](int buf, int k0) {
        async16(A + (size_t)(m0 + arow) * 512 + k0 + acs,
                &Ash[buf][wave * 512 + lane * 8]);
        async16(W16 + (size_t)(nb + wrow0) * 512 + k0 + wcs0,
                &Bsh[buf][wave * 512 + lane * 8]);
        async16(W16 + (size_t)(nb + wrow1) * 512 + k0 + wcs1,
                &Bsh[buf][(wave + 4) * 512 + lane * 8]);
    };

    floatx4 acc[2][4];
    for (int i = 0; i < 2; i++)
        for (int j = 0; j < 4; j++) acc[i][j] = (floatx4){0.f, 0.f, 0.f, 0.f};

    dma(0, 0);
    for (int kt = 0; kt < 16; ++kt) {
        const int cur = kt & 1;
        __syncthreads();
        if (kt < 15) dma(1 - cur, (kt + 1) * 32);

        short8 af[2], bf[4];
        for (int i = 0; i < 2; i++) {
            int r = wr * 32 + i * 16 + ln;
            af[i] = *(const short8*)&Ash[cur][r * 32 + ((quad ^ ((r >> 1) & 3)) << 3)];
        }
        for (int j = 0; j < 4; j++) {
            int r = wc * 64 + j * 16 + ln;
            bf[j] = *(const short8*)&Bsh[cur][r * 32 + ((quad ^ ((r >> 1) & 3)) << 3)];
        }
        for (int i = 0; i < 2; i++)
            for (int j = 0; j < 4; j++)
                acc[i][j] = __builtin_amdgcn_mfma_f32_16x16x32_bf16(af[i], bf[j], acc[i][j], 0, 0, 0);
    }

    for (int i = 0; i < 2; i++) {
        int row = m0 + wr * 32 + i * 16 + quad * 4;
        for (int j = 0; j < 4; j++) {
            int col = nb + wc * 64 + j * 16 + ln;
            float bv = bias[col];
            #pragma unroll
            for (int r = 0; r < 4; r++)
                out[(size_t)(row + r) * 512 + col] = acc[i][j][r] + bv;
        }
    }
}

extern "C" void kernel_launch(void* const* d_in, const int* in_sizes, int n_in,
                              void* d_out, int out_size, void* d_ws, size_t ws_size,
                              hipStream_t stream) {
    const float* Q    = (const float*)d_in[0];
    const float* K    = (const float*)d_in[1];
    const float* V    = (const float*)d_in[2];
    const float* sig  = (const float*)d_in[3];
    const float* lam  = (const float*)d_in[4];
    const float* W    = (const float*)d_in[5];
    const float* bias = (const float*)d_in[6];

    unsigned short* K16 = (unsigned short*)d_ws;                          // 8 MB
    unsigned short* Vt  = (unsigned short*)((char*)d_ws + (8u << 20));    // 8 MB
    unsigned short* ctx = (unsigned short*)((char*)d_ws + (16u << 20));   // 8 MB
    unsigned short* W16 = (unsigned short*)((char*)d_ws + (24u << 20));   // 512 KB
    unsigned* flags     = (unsigned*)((char*)d_ws + (24u << 20) + (512u << 10)); // 64 B
    float* out = (float*)d_out;

    zero_kernel<<<dim3(1), dim3(64), 0, stream>>>(flags);
    attn_kernel<<<dim3(512), dim3(512), 0, stream>>>(
        Q, K, V, W, sig, lam, K16, Vt, W16, flags, ctx);
    proj_kernel<<<dim3(4, 128), dim3(256), 0, stream>>>(ctx, W16, bias, out);
}

// Round 6
// 276.800 us; speedup vs baseline: 1.6279x; 1.6279x over previous
//
#include <hip/hip_runtime.h>
#include <hip/hip_bf16.h>

// VolatilityModulatedAttention: B=2, S=4096, H=512, NH=8, HD=64
// Round 12: revert to validated R9 3-kernel structure (device-barrier fusion
// abandoned: R10 killed container, R11's agent-scope fences thrashed L2 ->
// 450us). Attn occupancy doubled: 1024-thread blocks (16 waves = 2 K-split
// groups x 8 waves, each wave owns 16 Q-rows) -> 2 blocks/CU x 16 waves =
// 32 waves/CU (HW max) vs 16 before. All LDS layouts/swizzles/permutation/
// epilogue identical to R9. VALU trims: pack_trunc in hot loop (validated in
// R11 pass), rk fma-form (exact). __launch_bounds__(1024,8) caps VGPR at 64.

#define S_LEN 4096
#define HD 64
#define HTOT 512

typedef __attribute__((ext_vector_type(8))) short short8;
typedef __attribute__((ext_vector_type(4))) float floatx4;

#if __has_builtin(__builtin_amdgcn_exp2f)
#define EXP2F(x) __builtin_amdgcn_exp2f(x)
#else
#define EXP2F(x) exp2f(x)
#endif

__device__ __forceinline__ unsigned pack_bf16(float a, float b) {
    unsigned ua = __builtin_bit_cast(unsigned, a) + 0x8000u;
    unsigned ub = __builtin_bit_cast(unsigned, b) + 0x8000u;
    return __builtin_amdgcn_perm(ub, ua, 0x07060302u);
}

// truncation pack (no rounding adds). P only: O and L consume the same stored
// P, so the uniform truncation bias cancels in O/L. Validated in R11's pass.
__device__ __forceinline__ unsigned pack_trunc(float a, float b) {
    return __builtin_amdgcn_perm(__builtin_bit_cast(unsigned, b),
                                 __builtin_bit_cast(unsigned, a), 0x07060302u);
}

__device__ __forceinline__ unsigned short f2bf(float x) {
    unsigned u = __builtin_bit_cast(unsigned, x) + 0x8000u;
    return (unsigned short)(u >> 16);
}

__device__ __forceinline__ void async16(const unsigned short* g, unsigned short* l) {
    __builtin_amdgcn_global_load_lds(
        (const __attribute__((address_space(1))) unsigned int*)g,
        (__attribute__((address_space(3))) unsigned int*)l, 16, 0, 0);
}

// ---------------------------------------------------------------------------
// Fused prepass. [0,2048): K fp32->bf16. [2048,3072): V per-head transpose
// Vt[B*8][64][4096]. [3072,3200): W fp32->bf16.  (R9 verbatim)
// ---------------------------------------------------------------------------
__global__ __launch_bounds__(256) void prep_kernel(
    const float* __restrict__ K, unsigned short* __restrict__ K16,
    const float* __restrict__ V, unsigned short* __restrict__ Vt,
    const float* __restrict__ W, unsigned short* __restrict__ W16)
{
    const int tid = threadIdx.x;
    if (blockIdx.x >= 3072) {
        size_t i = ((size_t)(blockIdx.x - 3072) * 256 + tid) * 8;
        float4 a = *(const float4*)(W + i);
        float4 b = *(const float4*)(W + i + 4);
        unsigned o[4] = {pack_bf16(a.x, a.y), pack_bf16(a.z, a.w),
                         pack_bf16(b.x, b.y), pack_bf16(b.z, b.w)};
        *(short8*)(W16 + i) = *(short8*)o;
    } else if (blockIdx.x < 2048) {
        size_t i = ((size_t)blockIdx.x * 256 + tid) * 8;
        float4 a = *(const float4*)(K + i);
        float4 b = *(const float4*)(K + i + 4);
        unsigned o[4] = {pack_bf16(a.x, a.y), pack_bf16(a.z, a.w),
                         pack_bf16(b.x, b.y), pack_bf16(b.z, b.w)};
        *(short8*)(K16 + i) = *(short8*)o;
    } else {
        __shared__ unsigned short T[64 * 66];   // [d][s]
        const int blk = blockIdx.x - 2048;
        const int st = blk & 63;
        const int bh = blk >> 6;
        const int b = bh >> 3, h = bh & 7;
        const float* src = V + ((size_t)b * S_LEN + st * 64) * HTOT + h * HD;
        for (int i = 0; i < 4; i++) {
            int idx = tid + i * 256;
            int s = idx >> 4, c4 = idx & 15;
            float4 v = *(const float4*)(src + (size_t)s * HTOT + c4 * 4);
            T[(c4 * 4 + 0) * 66 + s] = f2bf(v.x);
            T[(c4 * 4 + 1) * 66 + s] = f2bf(v.y);
            T[(c4 * 4 + 2) * 66 + s] = f2bf(v.z);
            T[(c4 * 4 + 3) * 66 + s] = f2bf(v.w);
        }
        __syncthreads();
        unsigned short* dst = Vt + ((size_t)bh * 64) * S_LEN + st * 64;
        for (int i = 0; i < 2; i++) {
            int idx = tid + i * 256;
            int d = idx >> 3, c8 = idx & 7;
            uint2 lo = *(const uint2*)&T[d * 66 + c8 * 8];
            uint2 hi = *(const uint2*)&T[d * 66 + c8 * 8 + 4];
            unsigned o[4] = {lo.x, lo.y, hi.x, hi.y};
            *(short8*)(dst + (size_t)d * S_LEN + c8 * 8) = *(short8*)o;
        }
    }
}

// ---------------------------------------------------------------------------
// Flash attention. Grid 512 = (b*8+h)*32+qt, block 1024 thr = 16 waves:
// grp = wave>>3 (K-split half), wv = wave&7 (owns Q rows wv*16..+16).
// Waves 0-3 of each group stage K (permuted rows: R7 mapping), waves 4-7
// stage V. P stays in registers; f32 LDS combine epilogue (R9 verbatim).
// LDS 64KB: [grp][buf][K 4096|V 4096] shorts -> 2 blocks/CU, 32 waves/CU.
// ---------------------------------------------------------------------------
__global__ __launch_bounds__(1024, 8) void attn_kernel(
    const float* __restrict__ Q, const unsigned short* __restrict__ K16,
    const unsigned short* __restrict__ Vt,
    const float* __restrict__ risk_sigma, const float* __restrict__ risk_lambda,
    unsigned short* __restrict__ ctx)
{
    __shared__ unsigned short SH[32768];   // 64 KiB

    const int tid  = threadIdx.x;
    const int wave = tid >> 6;             // 0..15
    const int grp  = wave >> 3;            // K-split half
    const int wv   = wave & 7;             // wave within group
    const int lane = tid & 63;
    const int quad = lane >> 4;
    const int ln   = lane & 15;
    const int sw   = ln & 7;

    const int bid = blockIdx.x;            // (b*8+h)*32+qt
    const int qt  = bid & 31;
    const int h   = (bid >> 5) & 7;
    const int b   = bid >> 8;
    const int qbase = qt * 128;

    float sig = risk_sigma[b];
    sig = fminf(fmaxf(sig, 0.001f), 0.2f);
    const float sn   = (sig - 0.001f) * (1.0f / 0.199f);
    const float coef = risk_lambda[0] * 0.1f * sn;
    const float nc2 = -coef * (1.0f / 4096.0f) * (1.0f / 4096.0f) * 1.4426950408889634f;
    const float b1c = nc2, b4c = 4.0f * nc2, b9c = 9.0f * nc2;
    const float qscale = 0.125f * 1.4426950408889634f;

    const float* Qb = Q + (size_t)b * S_LEN * HTOT + (size_t)h * HD;
    const unsigned short* Kb = K16 + (size_t)b * S_LEN * HTOT + (size_t)h * HD;
    const unsigned short* Vb = Vt + ((size_t)(b * 8 + h) * 64) * S_LEN;

    const int rl  = lane >> 3;
    const int c8g = ((lane & 7) ^ rl) << 3;
    const int ws  = wv & 3;                // stager index within K/V team
    // permuted K source row for LDS dest row rr = ws*8+rl (and rr+32):
    // src = [r3 r2 r4 r1 r0] of rr's low 5 bits (R7 mapping)
    const int ksrow = ((ws & 1) << 4) | (((rl >> 2) & 1) << 3)
                    | ((ws >> 1) << 2) | (rl & 3);

    auto dma = [&](int buf, int kb) {
        unsigned short* base = SH + (grp * 2 + buf) * 8192;   // K at +0, V at +4096
        if (wv < 4) {
            const unsigned short* gk = Kb + (size_t)(kb + ksrow) * HTOT + c8g;
            async16(gk,             base + ws * 512 + lane * 8);
            async16(gk + 32 * HTOT, base + (ws + 4) * 512 + lane * 8);
        } else {
            const unsigned short* gv = Vb + (size_t)(ws * 8 + rl) * S_LEN + kb + c8g;
            async16(gv,              base + 4096 + ws * 512 + lane * 8);
            async16(gv + 32 * S_LEN, base + 4096 + (ws + 4) * 512 + lane * 8);
        }
    };

    const int kb0 = grp * 2048;
    dma(0, kb0);

    // Q fragment straight from global (16 rows per wave), qscale folded.
    short8 qf[2];
    {
        const float* qp = Qb + (size_t)(qbase + wv * 16 + ln) * HTOT + quad * 8;
        #pragma unroll
        for (int hf = 0; hf < 2; hf++) {
            float4 x = *(const float4*)(qp + hf * 32);
            float4 y = *(const float4*)(qp + hf * 32 + 4);
            unsigned o[4] = {pack_bf16(x.x * qscale, x.y * qscale),
                             pack_bf16(x.z * qscale, x.w * qscale),
                             pack_bf16(y.x * qscale, y.y * qscale),
                             pack_bf16(y.z * qscale, y.w * qscale)};
            qf[hf] = *(short8*)o;
        }
    }
    __syncthreads();   // drains dma(0)

    const short sone = (short)0x3F80;
    const short8 ones = {sone, sone, sone, sone, sone, sone, sone, sone};

    floatx4 Oacc[4], Lacc;
    Lacc = (floatx4){0.f, 0.f, 0.f, 0.f};
    #pragma unroll
    for (int dt = 0; dt < 4; dt++) Oacc[dt] = (floatx4){0.f, 0.f, 0.f, 0.f};

    const int qa = qbase + wv * 16;
    const float quad8f = (float)(quad * 8);

    for (int kt = 0; kt < 32; ++kt) {
        const int kbase = kb0 + kt * 64;
        const int cur = kt & 1;
        if (kt < 31) dma(1 - cur, kbase + 64);
        const unsigned short* Kc = SH + (grp * 2 + cur) * 8192;
        const unsigned short* Vc = Kc + 4096;

        const float dqq = (float)(qa + ln - kbase) - quad8f;
        unsigned pw[2][4];   // [part][word] — PV A-fragments

        #pragma unroll
        for (int jt = 0; jt < 4; jt++) {
            const int krow = (jt * 16 + ln) * 64;
            short8 ak0 = *(const short8*)&Kc[krow + ((quad ^ sw) << 3)];
            short8 ak1 = *(const short8*)&Kc[krow + (((quad + 4) ^ sw) << 3)];
            // rk[r] = nc2*(d0-r)^2 = t - 2r*s + r^2*nc2  (exact fma form)
            const float d0 = dqq - (float)((jt >> 1) * 32 + (jt & 1) * 4);
            const float s1 = nc2 * d0;
            const float t  = s1 * d0;
            floatx4 rk;
            rk[0] = t;
            rk[1] = __builtin_fmaf(-2.0f, s1, t) + b1c;
            rk[2] = __builtin_fmaf(-4.0f, s1, t) + b4c;
            rk[3] = __builtin_fmaf(-6.0f, s1, t) + b9c;
            floatx4 s = __builtin_amdgcn_mfma_f32_16x16x32_bf16(ak0, qf[0], rk, 0, 0, 0);
            s = __builtin_amdgcn_mfma_f32_16x16x32_bf16(ak1, qf[1], s, 0, 0, 0);
            float p0 = EXP2F(s[0]);
            float p1 = EXP2F(s[1]);
            float p2 = EXP2F(s[2]);
            float p3 = EXP2F(s[3]);
            pw[jt >> 1][(jt & 1) * 2 + 0] = pack_trunc(p0, p1);
            pw[jt >> 1][(jt & 1) * 2 + 1] = pack_trunc(p2, p3);
        }

        __builtin_amdgcn_s_setprio(1);
        short8 pa0 = *(const short8*)&pw[0][0];
        short8 pa1 = *(const short8*)&pw[1][0];
        #pragma unroll
        for (int dt = 0; dt < 4; dt++) {
            const int vrow = (dt * 16 + ln) * 64;
            short8 bv0 = *(const short8*)&Vc[vrow + ((quad ^ sw) << 3)];
            short8 bv1 = *(const short8*)&Vc[vrow + (((quad + 4) ^ sw) << 3)];
            Oacc[dt] = __builtin_amdgcn_mfma_f32_16x16x32_bf16(pa0, bv0, Oacc[dt], 0, 0, 0);
            Oacc[dt] = __builtin_amdgcn_mfma_f32_16x16x32_bf16(pa1, bv1, Oacc[dt], 0, 0, 0);
        }
        Lacc = __builtin_amdgcn_mfma_f32_16x16x32_bf16(pa0, ones, Lacc, 0, 0, 0);
        Lacc = __builtin_amdgcn_mfma_f32_16x16x32_bf16(pa1, ones, Lacc, 0, 0, 0);
        __builtin_amdgcn_s_setprio(0);
        __syncthreads();
    }

    // ---- epilogue: cross-group combine in LDS (f32), direct ctx write ----
    float* X   = (float*)SH;               // [128][68] f32
    float* Lsh = (float*)SH + 128 * 68;    // [2][128] f32

    if (ln == 0) {
        #pragma unroll
        for (int r = 0; r < 4; r++)
            Lsh[grp * 128 + wv * 16 + quad * 4 + r] = Lacc[r];
    }
    if (grp == 0) {
        #pragma unroll
        for (int dt = 0; dt < 4; dt++)
            #pragma unroll
            for (int r = 0; r < 4; r++)
                X[(wv * 16 + quad * 4 + r) * 68 + dt * 16 + ln] = Oacc[dt][r];
    }
    __syncthreads();
    if (grp == 1) {
        float inv[4];
        #pragma unroll
        for (int r = 0; r < 4; r++) {
            int row = wv * 16 + quad * 4 + r;
            inv[r] = 1.0f / (Lsh[row] + Lsh[128 + row]);
        }
        #pragma unroll
        for (int dt = 0; dt < 4; dt++)
            #pragma unroll
            for (int r = 0; r < 4; r++) {
                int row = wv * 16 + quad * 4 + r;
                float* p = &X[row * 68 + dt * 16 + ln];
                *p = (*p + Oacc[dt][r]) * inv[r];
            }
    }
    __syncthreads();
    {
        const int q = tid >> 3;            // 128 rows, 8 threads/row
        const int c = tid & 7;             // 8-col chunk
        const float* xp = X + q * 68 + c * 8;
        float4 x0 = *(const float4*)(xp + 0);
        float4 x1 = *(const float4*)(xp + 4);
        unsigned o0[4] = {pack_bf16(x0.x, x0.y), pack_bf16(x0.z, x0.w),
                          pack_bf16(x1.x, x1.y), pack_bf16(x1.z, x1.w)};
        unsigned short* cp = ctx + ((size_t)b * S_LEN + qbase + q) * HTOT + h * HD + c * 8;
        *(short8*)cp = *(short8*)o0;
    }
}

// ---------------------------------------------------------------------------
// Projection GEMM, all-bf16, DMA double-buffered staging. (R9 verbatim)
// ---------------------------------------------------------------------------
__global__ __launch_bounds__(256) void proj_kernel(
    const unsigned short* __restrict__ A,   // ctx bf16 [8192 x 512]
    const unsigned short* __restrict__ W16, // [512 x 512] bf16
    const float* __restrict__ bias,
    float* __restrict__ out)
{
    __shared__ unsigned short Ash[2][64 * 32];
    __shared__ unsigned short Bsh[2][128 * 32];
    const int tid = threadIdx.x;
    const int wave = tid >> 6, lane = tid & 63, quad = lane >> 4, ln = lane & 15;
    const int wr = wave >> 1, wc = wave & 1;
    const int m0 = blockIdx.y * 64;
    const int nb = blockIdx.x * 128;

    const int arow = (wave * 64 + lane) >> 2;
    const int ac   = (wave * 64 + lane) & 3;
    const int acs  = (ac ^ ((arow >> 1) & 3)) << 3;
    const int wrow0 = (wave * 64 + lane) >> 2;
    const int wc0   = (wave * 64 + lane) & 3;
    const int wcs0  = (wc0 ^ ((wrow0 >> 1) & 3)) << 3;
    const int wrow1 = wrow0 + 64;
    const int wcs1  = (wc0 ^ ((wrow1 >> 1) & 3)) << 3;

    auto dma = [&](int buf, int k0) {
        async16(A + (size_t)(m0 + arow) * 512 + k0 + acs,
                &Ash[buf][wave * 512 + lane * 8]);
        async16(W16 + (size_t)(nb + wrow0) * 512 + k0 + wcs0,
                &Bsh[buf][wave * 512 + lane * 8]);
        async16(W16 + (size_t)(nb + wrow1) * 512 + k0 + wcs1,
                &Bsh[buf][(wave + 4) * 512 + lane * 8]);
    };

    floatx4 acc[2][4];
    for (int i = 0; i < 2; i++)
        for (int j = 0; j < 4; j++) acc[i][j] = (floatx4){0.f, 0.f, 0.f, 0.f};

    dma(0, 0);
    for (int kt = 0; kt < 16; ++kt) {
        const int cur = kt & 1;
        __syncthreads();
        if (kt < 15) dma(1 - cur, (kt + 1) * 32);

        short8 af[2], bf[4];
        for (int i = 0; i < 2; i++) {
            int r = wr * 32 + i * 16 + ln;
            af[i] = *(const short8*)&Ash[cur][r * 32 + ((quad ^ ((r >> 1) & 3)) << 3)];
        }
        for (int j = 0; j < 4; j++) {
            int r = wc * 64 + j * 16 + ln;
            bf[j] = *(const short8*)&Bsh[cur][r * 32 + ((quad ^ ((r >> 1) & 3)) << 3)];
        }
        for (int i = 0; i < 2; i++)
            for (int j = 0; j < 4; j++)
                acc[i][j] = __builtin_amdgcn_mfma_f32_16x16x32_bf16(af[i], bf[j], acc[i][j], 0, 0, 0);
    }

    for (int i = 0; i < 2; i++) {
        int row = m0 + wr * 32 + i * 16 + quad * 4;
        for (int j = 0; j < 4; j++) {
            int col = nb + wc * 64 + j * 16 + ln;
            float bv = bias[col];
            #pragma unroll
            for (int r = 0; r < 4; r++)
                out[(size_t)(row + r) * 512 + col] = acc[i][j][r] + bv;
        }
    }
}

extern "C" void kernel_launch(void* const* d_in, const int* in_sizes, int n_in,
                              void* d_out, int out_size, void* d_ws, size_t ws_size,
                              hipStream_t stream) {
    const float* Q    = (const float*)d_in[0];
    const float* K    = (const float*)d_in[1];
    const float* V    = (const float*)d_in[2];
    const float* sig  = (const float*)d_in[3];
    const float* lam  = (const float*)d_in[4];
    const float* W    = (const float*)d_in[5];
    const float* bias = (const float*)d_in[6];

    unsigned short* K16 = (unsigned short*)d_ws;                          // 8 MB
    unsigned short* Vt  = (unsigned short*)((char*)d_ws + (8u << 20));    // 8 MB
    unsigned short* ctx = (unsigned short*)((char*)d_ws + (16u << 20));   // 8 MB
    unsigned short* W16 = (unsigned short*)((char*)d_ws + (24u << 20));   // 512 KB
    float* out = (float*)d_out;

    prep_kernel<<<dim3(3200), dim3(256), 0, stream>>>(K, K16, V, Vt, W, W16);
    attn_kernel<<<dim3(512), dim3(1024), 0, stream>>>(Q, K16, Vt, sig, lam, ctx);
    proj_kernel<<<dim3(4, 128), dim3(256), 0, stream>>>(ctx, W16, bias, out);
}

// Round 7
// 200.164 us; speedup vs baseline: 2.2512x; 1.3829x over previous
//
#include <hip/hip_runtime.h>
#include <hip/hip_bf16.h>

// VolatilityModulatedAttention: B=2, S=4096, H=512, NH=8, HD=64
// Round 13: exact R9 structure (best validated: 201.3us) + the two trims that
// each passed validation in later rounds: pack_trunc for hot-loop P packing
// (R11 pass) and rk fma-form (R12 pass). No structural changes. R10-R12
// post-mortems: device barriers thrash L2 (450us), launch_bounds occupancy
// forcing spills to scratch (277us) — attn's design point is 8-wave blocks,
// VGPR 64, 16 waves/CU; the remaining lever is issued-VALU reduction.

#define S_LEN 4096
#define HD 64
#define HTOT 512

typedef __attribute__((ext_vector_type(8))) short short8;
typedef __attribute__((ext_vector_type(4))) float floatx4;

#if __has_builtin(__builtin_amdgcn_exp2f)
#define EXP2F(x) __builtin_amdgcn_exp2f(x)
#else
#define EXP2F(x) exp2f(x)
#endif

__device__ __forceinline__ unsigned pack_bf16(float a, float b) {
    unsigned ua = __builtin_bit_cast(unsigned, a) + 0x8000u;
    unsigned ub = __builtin_bit_cast(unsigned, b) + 0x8000u;
    return __builtin_amdgcn_perm(ub, ua, 0x07060302u);
}

// truncation pack (no rounding adds). P only: O and L consume the same stored
// P, so the uniform truncation bias cancels in O/L. Validated R11/R12.
__device__ __forceinline__ unsigned pack_trunc(float a, float b) {
    return __builtin_amdgcn_perm(__builtin_bit_cast(unsigned, b),
                                 __builtin_bit_cast(unsigned, a), 0x07060302u);
}

__device__ __forceinline__ unsigned short f2bf(float x) {
    unsigned u = __builtin_bit_cast(unsigned, x) + 0x8000u;
    return (unsigned short)(u >> 16);
}

__device__ __forceinline__ void async16(const unsigned short* g, unsigned short* l) {
    __builtin_amdgcn_global_load_lds(
        (const __attribute__((address_space(1))) unsigned int*)g,
        (__attribute__((address_space(3))) unsigned int*)l, 16, 0, 0);
}

// ---------------------------------------------------------------------------
// Fused prepass. [0,2048): K fp32->bf16. [2048,3072): V per-head transpose
// Vt[B*8][64][4096]. [3072,3200): W fp32->bf16.  (R9 verbatim)
// ---------------------------------------------------------------------------
__global__ __launch_bounds__(256) void prep_kernel(
    const float* __restrict__ K, unsigned short* __restrict__ K16,
    const float* __restrict__ V, unsigned short* __restrict__ Vt,
    const float* __restrict__ W, unsigned short* __restrict__ W16)
{
    const int tid = threadIdx.x;
    if (blockIdx.x >= 3072) {
        size_t i = ((size_t)(blockIdx.x - 3072) * 256 + tid) * 8;
        float4 a = *(const float4*)(W + i);
        float4 b = *(const float4*)(W + i + 4);
        unsigned o[4] = {pack_bf16(a.x, a.y), pack_bf16(a.z, a.w),
                         pack_bf16(b.x, b.y), pack_bf16(b.z, b.w)};
        *(short8*)(W16 + i) = *(short8*)o;
    } else if (blockIdx.x < 2048) {
        size_t i = ((size_t)blockIdx.x * 256 + tid) * 8;
        float4 a = *(const float4*)(K + i);
        float4 b = *(const float4*)(K + i + 4);
        unsigned o[4] = {pack_bf16(a.x, a.y), pack_bf16(a.z, a.w),
                         pack_bf16(b.x, b.y), pack_bf16(b.z, b.w)};
        *(short8*)(K16 + i) = *(short8*)o;
    } else {
        __shared__ unsigned short T[64 * 66];   // [d][s]
        const int blk = blockIdx.x - 2048;
        const int st = blk & 63;
        const int bh = blk >> 6;
        const int b = bh >> 3, h = bh & 7;
        const float* src = V + ((size_t)b * S_LEN + st * 64) * HTOT + h * HD;
        for (int i = 0; i < 4; i++) {
            int idx = tid + i * 256;
            int s = idx >> 4, c4 = idx & 15;
            float4 v = *(const float4*)(src + (size_t)s * HTOT + c4 * 4);
            T[(c4 * 4 + 0) * 66 + s] = f2bf(v.x);
            T[(c4 * 4 + 1) * 66 + s] = f2bf(v.y);
            T[(c4 * 4 + 2) * 66 + s] = f2bf(v.z);
            T[(c4 * 4 + 3) * 66 + s] = f2bf(v.w);
        }
        __syncthreads();
        unsigned short* dst = Vt + ((size_t)bh * 64) * S_LEN + st * 64;
        for (int i = 0; i < 2; i++) {
            int idx = tid + i * 256;
            int d = idx >> 3, c8 = idx & 7;
            uint2 lo = *(const uint2*)&T[d * 66 + c8 * 8];
            uint2 hi = *(const uint2*)&T[d * 66 + c8 * 8 + 4];
            unsigned o[4] = {lo.x, lo.y, hi.x, hi.y};
            *(short8*)(dst + (size_t)d * S_LEN + c8 * 8) = *(short8*)o;
        }
    }
}

// ---------------------------------------------------------------------------
// Flash attention, K-split internal: wave-groups 0-3 (ks=0) / 4-7 (ks=1) of a
// 512-thread block. Grid: 512 = (b*8+h)*32+qt. P stays in registers (R7
// permuted-K staging). Epilogue: f32 cross-group combine via LDS, direct
// bf16 ctx write. LDS 64KB. (R9 verbatim + pack_trunc + rk fma-form)
// ---------------------------------------------------------------------------
__global__ __launch_bounds__(512, 4) void attn_kernel(
    const float* __restrict__ Q, const unsigned short* __restrict__ K16,
    const unsigned short* __restrict__ Vt,
    const float* __restrict__ risk_sigma, const float* __restrict__ risk_lambda,
    unsigned short* __restrict__ ctx)
{
    __shared__ unsigned short SH[32768];   // 64 KiB

    const int tid  = threadIdx.x;
    const int wave = tid >> 6;
    const int grp  = wave >> 2;            // K-split half
    const int wv   = wave & 3;             // wave within group
    const int lane = tid & 63;
    const int quad = lane >> 4;
    const int ln   = lane & 15;
    const int sw   = ln & 7;

    const int bid = blockIdx.x;            // (b*8+h)*32+qt
    const int qt  = bid & 31;
    const int h   = (bid >> 5) & 7;
    const int b   = bid >> 8;
    const int qbase = qt * 128;

    float sig = risk_sigma[b];
    sig = fminf(fmaxf(sig, 0.001f), 0.2f);
    const float sn   = (sig - 0.001f) * (1.0f / 0.199f);
    const float coef = risk_lambda[0] * 0.1f * sn;
    const float nc2 = -coef * (1.0f / 4096.0f) * (1.0f / 4096.0f) * 1.4426950408889634f;
    const float b1c = nc2, b4c = 4.0f * nc2, b9c = 9.0f * nc2;
    const float qscale = 0.125f * 1.4426950408889634f;

    const float* Qb = Q + (size_t)b * S_LEN * HTOT + (size_t)h * HD;
    const unsigned short* Kb = K16 + (size_t)b * S_LEN * HTOT + (size_t)h * HD;
    const unsigned short* Vb = Vt + ((size_t)(b * 8 + h) * 64) * S_LEN;

    const int rl  = lane >> 3;
    const int c8g = ((lane & 7) ^ rl) << 3;
    // permuted K source row for LDS dest row rr = wv*8+rl:
    // src = [r3 r2 r4 r1 r0] of rr's low 5 bits (R7 mapping, per group)
    const int ksrow = ((wv & 1) << 4) | (((rl >> 2) & 1) << 3)
                    | ((wv >> 1) << 2) | (rl & 3);

    auto dma = [&](int buf, int kb) {
        unsigned short* base = SH + (grp * 2 + buf) * 8192;   // K at +0, V at +4096
        const unsigned short* gk = Kb + (size_t)(kb + ksrow) * HTOT + c8g;
        const unsigned short* gv = Vb + (size_t)(wv * 8 + rl) * S_LEN + kb + c8g;
        async16(gk,              base + wv * 512 + lane * 8);
        async16(gk + 32 * HTOT,  base + (wv + 4) * 512 + lane * 8);
        async16(gv,              base + 4096 + wv * 512 + lane * 8);
        async16(gv + 32 * S_LEN, base + 4096 + (wv + 4) * 512 + lane * 8);
    };

    const int kb0 = grp * 2048;
    dma(0, kb0);

    // Q fragments straight from global, qscale folded.
    short8 qf[2][2];
    {
        const float* qp0 = Qb + (size_t)(qbase + wv * 32 + ln) * HTOT + quad * 8;
        #pragma unroll
        for (int nt = 0; nt < 2; nt++) {
            const float* qp = qp0 + (size_t)(nt * 16) * HTOT;
            #pragma unroll
            for (int hf = 0; hf < 2; hf++) {
                float4 x = *(const float4*)(qp + hf * 32);
                float4 y = *(const float4*)(qp + hf * 32 + 4);
                unsigned o[4] = {pack_bf16(x.x * qscale, x.y * qscale),
                                 pack_bf16(x.z * qscale, x.w * qscale),
                                 pack_bf16(y.x * qscale, y.y * qscale),
                                 pack_bf16(y.z * qscale, y.w * qscale)};
                qf[nt][hf] = *(short8*)o;
            }
        }
    }
    __syncthreads();   // drains dma(0)

    const short sone = (short)0x3F80;
    const short8 ones = {sone, sone, sone, sone, sone, sone, sone, sone};

    floatx4 Oacc[2][4], Lacc[2];
    #pragma unroll
    for (int nt = 0; nt < 2; nt++) {
        Lacc[nt] = (floatx4){0.f, 0.f, 0.f, 0.f};
        #pragma unroll
        for (int dt = 0; dt < 4; dt++) Oacc[nt][dt] = (floatx4){0.f, 0.f, 0.f, 0.f};
    }

    const int qa = qbase + wv * 32;
    const float quad8f = (float)(quad * 8);

    for (int kt = 0; kt < 32; ++kt) {
        const int kbase = kb0 + kt * 64;
        const int cur = kt & 1;
        if (kt < 31) dma(1 - cur, kbase + 64);
        const unsigned short* Kc = SH + (grp * 2 + cur) * 8192;
        const unsigned short* Vc = Kc + 4096;

        const float dqq = (float)(qa + ln - kbase) - quad8f;
        unsigned pw[2][2][4];   // [nt][part][word] — PV A-fragments

        #pragma unroll
        for (int jt = 0; jt < 4; jt++) {
            const int krow = (jt * 16 + ln) * 64;
            short8 ak0 = *(const short8*)&Kc[krow + ((quad ^ sw) << 3)];
            short8 ak1 = *(const short8*)&Kc[krow + (((quad + 4) ^ sw) << 3)];
            const float jtoff = (float)((jt >> 1) * 32 + (jt & 1) * 4);
            #pragma unroll
            for (int nt = 0; nt < 2; nt++) {
                // rk[r] = nc2*(d0-r)^2 = t - 2r*(nc2*d0) + r^2*nc2 (exact fma
                // form, validated R12)
                const float d0 = dqq + ((float)(nt * 16) - jtoff);
                const float s1 = nc2 * d0;
                const float t  = s1 * d0;
                floatx4 rk;
                rk[0] = t;
                rk[1] = __builtin_fmaf(-2.0f, s1, t) + b1c;
                rk[2] = __builtin_fmaf(-4.0f, s1, t) + b4c;
                rk[3] = __builtin_fmaf(-6.0f, s1, t) + b9c;
                floatx4 s = __builtin_amdgcn_mfma_f32_16x16x32_bf16(ak0, qf[nt][0], rk, 0, 0, 0);
                s = __builtin_amdgcn_mfma_f32_16x16x32_bf16(ak1, qf[nt][1], s, 0, 0, 0);
                float p0 = EXP2F(s[0]);
                float p1 = EXP2F(s[1]);
                float p2 = EXP2F(s[2]);
                float p3 = EXP2F(s[3]);
                pw[nt][jt >> 1][(jt & 1) * 2 + 0] = pack_trunc(p0, p1);
                pw[nt][jt >> 1][(jt & 1) * 2 + 1] = pack_trunc(p2, p3);
            }
        }

        __builtin_amdgcn_s_setprio(1);
        #pragma unroll
        for (int dt = 0; dt < 4; dt++) {
            const int vrow = (dt * 16 + ln) * 64;
            short8 bv0 = *(const short8*)&Vc[vrow + ((quad ^ sw) << 3)];
            short8 bv1 = *(const short8*)&Vc[vrow + (((quad + 4) ^ sw) << 3)];
            #pragma unroll
            for (int nt = 0; nt < 2; nt++) {
                short8 pa0 = *(const short8*)&pw[nt][0][0];
                short8 pa1 = *(const short8*)&pw[nt][1][0];
                Oacc[nt][dt] = __builtin_amdgcn_mfma_f32_16x16x32_bf16(pa0, bv0, Oacc[nt][dt], 0, 0, 0);
                Oacc[nt][dt] = __builtin_amdgcn_mfma_f32_16x16x32_bf16(pa1, bv1, Oacc[nt][dt], 0, 0, 0);
            }
        }
        #pragma unroll
        for (int nt = 0; nt < 2; nt++) {
            short8 pa0 = *(const short8*)&pw[nt][0][0];
            short8 pa1 = *(const short8*)&pw[nt][1][0];
            Lacc[nt] = __builtin_amdgcn_mfma_f32_16x16x32_bf16(pa0, ones, Lacc[nt], 0, 0, 0);
            Lacc[nt] = __builtin_amdgcn_mfma_f32_16x16x32_bf16(pa1, ones, Lacc[nt], 0, 0, 0);
        }
        __builtin_amdgcn_s_setprio(0);
        __syncthreads();
    }

    // ---- epilogue: cross-group combine in LDS (f32), direct ctx write ----
    float* X   = (float*)SH;               // [128][68] f32
    float* Lsh = (float*)SH + 128 * 68;    // [2][128] f32

    if (ln == 0) {
        #pragma unroll
        for (int nt = 0; nt < 2; nt++)
            #pragma unroll
            for (int r = 0; r < 4; r++)
                Lsh[grp * 128 + wv * 32 + nt * 16 + quad * 4 + r] = Lacc[nt][r];
    }
    if (grp == 0) {
        #pragma unroll
        for (int nt = 0; nt < 2; nt++)
            #pragma unroll
            for (int dt = 0; dt < 4; dt++)
                #pragma unroll
                for (int r = 0; r < 4; r++)
                    X[(wv * 32 + nt * 16 + quad * 4 + r) * 68 + dt * 16 + ln] = Oacc[nt][dt][r];
    }
    __syncthreads();
    if (grp == 1) {
        #pragma unroll
        for (int nt = 0; nt < 2; nt++) {
            float inv[4];
            #pragma unroll
            for (int r = 0; r < 4; r++) {
                int row = wv * 32 + nt * 16 + quad * 4 + r;
                inv[r] = 1.0f / (Lsh[row] + Lsh[128 + row]);
            }
            #pragma unroll
            for (int dt = 0; dt < 4; dt++)
                #pragma unroll
                for (int r = 0; r < 4; r++) {
                    int row = wv * 32 + nt * 16 + quad * 4 + r;
                    float* p = &X[row * 68 + dt * 16 + ln];
                    *p = (*p + Oacc[nt][dt][r]) * inv[r];
                }
        }
    }
    __syncthreads();
    {
        const int q = tid >> 2;            // 128 rows, 4 threads/row
        const int c = tid & 3;             // 16-d chunk
        const float* xp = X + q * 68 + c * 16;
        float4 x0 = *(const float4*)(xp + 0);
        float4 x1 = *(const float4*)(xp + 4);
        float4 x2 = *(const float4*)(xp + 8);
        float4 x3 = *(const float4*)(xp + 12);
        unsigned o0[4] = {pack_bf16(x0.x, x0.y), pack_bf16(x0.z, x0.w),
                          pack_bf16(x1.x, x1.y), pack_bf16(x1.z, x1.w)};
        unsigned o1[4] = {pack_bf16(x2.x, x2.y), pack_bf16(x2.z, x2.w),
                          pack_bf16(x3.x, x3.y), pack_bf16(x3.z, x3.w)};
        unsigned short* cp = ctx + ((size_t)b * S_LEN + qbase + q) * HTOT + h * HD + c * 16;
        *(short8*)cp       = *(short8*)o0;
        *(short8*)(cp + 8) = *(short8*)o1;
    }
}

// ---------------------------------------------------------------------------
// Projection GEMM, all-bf16, DMA double-buffered staging. (R9 verbatim)
// ---------------------------------------------------------------------------
__global__ __launch_bounds__(256) void proj_kernel(
    const unsigned short* __restrict__ A,   // ctx bf16 [8192 x 512]
    const unsigned short* __restrict__ W16, // [512 x 512] bf16
    const float* __restrict__ bias,
    float* __restrict__ out)
{
    __shared__ unsigned short Ash[2][64 * 32];
    __shared__ unsigned short Bsh[2][128 * 32];
    const int tid = threadIdx.x;
    const int wave = tid >> 6, lane = tid & 63, quad = lane >> 4, ln = lane & 15;
    const int wr = wave >> 1, wc = wave & 1;
    const int m0 = blockIdx.y * 64;
    const int nb = blockIdx.x * 128;

    const int arow = (wave * 64 + lane) >> 2;
    const int ac   = (wave * 64 + lane) & 3;
    const int acs  = (ac ^ ((arow >> 1) & 3)) << 3;
    const int wrow0 = (wave * 64 + lane) >> 2;
    const int wc0   = (wave * 64 + lane) & 3;
    const int wcs0  = (wc0 ^ ((wrow0 >> 1) & 3)) << 3;
    const int wrow1 = wrow0 + 64;
    const int wcs1  = (wc0 ^ ((wrow1 >> 1) & 3)) << 3;

    auto dma = [&](int buf, int k0) {
        async16(A + (size_t)(m0 + arow) * 512 + k0 + acs,
                &Ash[buf][wave * 512 + lane * 8]);
        async16(W16 + (size_t)(nb + wrow0) * 512 + k0 + wcs0,
                &Bsh[buf][wave * 512 + lane * 8]);
        async16(W16 + (size_t)(nb + wrow1) * 512 + k0 + wcs1,
                &Bsh[buf][(wave + 4) * 512 + lane * 8]);
    };

    floatx4 acc[2][4];
    for (int i = 0; i < 2; i++)
        for (int j = 0; j < 4; j++) acc[i][j] = (floatx4){0.f, 0.f, 0.f, 0.f};

    dma(0, 0);
    for (int kt = 0; kt < 16; ++kt) {
        const int cur = kt & 1;
        __syncthreads();
        if (kt < 15) dma(1 - cur, (kt + 1) * 32);

        short8 af[2], bf[4];
        for (int i = 0; i < 2; i++) {
            int r = wr * 32 + i * 16 + ln;
            af[i] = *(const short8*)&Ash[cur][r * 32 + ((quad ^ ((r >> 1) & 3)) << 3)];
        }
        for (int j = 0; j < 4; j++) {
            int r = wc * 64 + j * 16 + ln;
            bf[j] = *(const short8*)&Bsh[cur][r * 32 + ((quad ^ ((r >> 1) & 3)) << 3)];
        }
        for (int i = 0; i < 2; i++)
            for (int j = 0; j < 4; j++)
                acc[i][j] = __builtin_amdgcn_mfma_f32_16x16x32_bf16(af[i], bf[j], acc[i][j], 0, 0, 0);
    }

    for (int i = 0; i < 2; i++) {
        int row = m0 + wr * 32 + i * 16 + quad * 4;
        for (int j = 0; j < 4; j++) {
            int col = nb + wc * 64 + j * 16 + ln;
            float bv = bias[col];
            #pragma unroll
            for (int r = 0; r < 4; r++)
                out[(size_t)(row + r) * 512 + col] = acc[i][j][r] + bv;
        }
    }
}

extern "C" void kernel_launch(void* const* d_in, const int* in_sizes, int n_in,
                              void* d_out, int out_size, void* d_ws, size_t ws_size,
                              hipStream_t stream) {
    const float* Q    = (const float*)d_in[0];
    const float* K    = (const float*)d_in[1];
    const float* V    = (const float*)d_in[2];
    const float* sig  = (const float*)d_in[3];
    const float* lam  = (const float*)d_in[4];
    const float* W    = (const float*)d_in[5];
    const float* bias = (const float*)d_in[6];

    unsigned short* K16 = (unsigned short*)d_ws;                          // 8 MB
    unsigned short* Vt  = (unsigned short*)((char*)d_ws + (8u << 20));    // 8 MB
    unsigned short* ctx = (unsigned short*)((char*)d_ws + (16u << 20));   // 8 MB
    unsigned short* W16 = (unsigned short*)((char*)d_ws + (24u << 20));   // 512 KB
    float* out = (float*)d_out;

    prep_kernel<<<dim3(3200), dim3(256), 0, stream>>>(K, K16, V, Vt, W, W16);
    attn_kernel<<<dim3(512), dim3(512), 0, stream>>>(Q, K16, Vt, sig, lam, ctx);
    proj_kernel<<<dim3(4, 128), dim3(256), 0, stream>>>(ctx, W16, bias, out);
}

// Round 8
// 190.343 us; speedup vs baseline: 2.3674x; 1.0516x over previous
//
#include <hip/hip_runtime.h>
#include <hip/hip_bf16.h>

// VolatilityModulatedAttention: B=2, S=4096, H=512, NH=8, HD=64
// Round 14: R13 structure (best: 200.2us) with addressing strength-reduction
// in the attn hot loop only: kt unrolled x2 so the LDS double-buffer index is
// compile-time -> 8 hoisted LDS base pointers with jt/dt*2048B folding into
// ds_read immediate offsets; global prefetch pointers advanced incrementally
// (+64 rows / +64 cols per kt); dqq incremental (no per-kt int->float chain).
// No layout/sync/numerics changes. prep/proj verbatim R13.

#define S_LEN 4096
#define HD 64
#define HTOT 512

typedef __attribute__((ext_vector_type(8))) short short8;
typedef __attribute__((ext_vector_type(4))) float floatx4;

#if __has_builtin(__builtin_amdgcn_exp2f)
#define EXP2F(x) __builtin_amdgcn_exp2f(x)
#else
#define EXP2F(x) exp2f(x)
#endif

__device__ __forceinline__ unsigned pack_bf16(float a, float b) {
    unsigned ua = __builtin_bit_cast(unsigned, a) + 0x8000u;
    unsigned ub = __builtin_bit_cast(unsigned, b) + 0x8000u;
    return __builtin_amdgcn_perm(ub, ua, 0x07060302u);
}

// truncation pack (no rounding adds). P only: O and L consume the same stored
// P, so the uniform truncation bias cancels in O/L. Validated R11/R12/R13.
__device__ __forceinline__ unsigned pack_trunc(float a, float b) {
    return __builtin_amdgcn_perm(__builtin_bit_cast(unsigned, b),
                                 __builtin_bit_cast(unsigned, a), 0x07060302u);
}

__device__ __forceinline__ unsigned short f2bf(float x) {
    unsigned u = __builtin_bit_cast(unsigned, x) + 0x8000u;
    return (unsigned short)(u >> 16);
}

__device__ __forceinline__ void async16(const unsigned short* g, unsigned short* l) {
    __builtin_amdgcn_global_load_lds(
        (const __attribute__((address_space(1))) unsigned int*)g,
        (__attribute__((address_space(3))) unsigned int*)l, 16, 0, 0);
}

// ---------------------------------------------------------------------------
// Fused prepass. [0,2048): K fp32->bf16. [2048,3072): V per-head transpose
// Vt[B*8][64][4096]. [3072,3200): W fp32->bf16.  (R13 verbatim)
// ---------------------------------------------------------------------------
__global__ __launch_bounds__(256) void prep_kernel(
    const float* __restrict__ K, unsigned short* __restrict__ K16,
    const float* __restrict__ V, unsigned short* __restrict__ Vt,
    const float* __restrict__ W, unsigned short* __restrict__ W16)
{
    const int tid = threadIdx.x;
    if (blockIdx.x >= 3072) {
        size_t i = ((size_t)(blockIdx.x - 3072) * 256 + tid) * 8;
        float4 a = *(const float4*)(W + i);
        float4 b = *(const float4*)(W + i + 4);
        unsigned o[4] = {pack_bf16(a.x, a.y), pack_bf16(a.z, a.w),
                         pack_bf16(b.x, b.y), pack_bf16(b.z, b.w)};
        *(short8*)(W16 + i) = *(short8*)o;
    } else if (blockIdx.x < 2048) {
        size_t i = ((size_t)blockIdx.x * 256 + tid) * 8;
        float4 a = *(const float4*)(K + i);
        float4 b = *(const float4*)(K + i + 4);
        unsigned o[4] = {pack_bf16(a.x, a.y), pack_bf16(a.z, a.w),
                         pack_bf16(b.x, b.y), pack_bf16(b.z, b.w)};
        *(short8*)(K16 + i) = *(short8*)o;
    } else {
        __shared__ unsigned short T[64 * 66];   // [d][s]
        const int blk = blockIdx.x - 2048;
        const int st = blk & 63;
        const int bh = blk >> 6;
        const int b = bh >> 3, h = bh & 7;
        const float* src = V + ((size_t)b * S_LEN + st * 64) * HTOT + h * HD;
        for (int i = 0; i < 4; i++) {
            int idx = tid + i * 256;
            int s = idx >> 4, c4 = idx & 15;
            float4 v = *(const float4*)(src + (size_t)s * HTOT + c4 * 4);
            T[(c4 * 4 + 0) * 66 + s] = f2bf(v.x);
            T[(c4 * 4 + 1) * 66 + s] = f2bf(v.y);
            T[(c4 * 4 + 2) * 66 + s] = f2bf(v.z);
            T[(c4 * 4 + 3) * 66 + s] = f2bf(v.w);
        }
        __syncthreads();
        unsigned short* dst = Vt + ((size_t)bh * 64) * S_LEN + st * 64;
        for (int i = 0; i < 2; i++) {
            int idx = tid + i * 256;
            int d = idx >> 3, c8 = idx & 7;
            uint2 lo = *(const uint2*)&T[d * 66 + c8 * 8];
            uint2 hi = *(const uint2*)&T[d * 66 + c8 * 8 + 4];
            unsigned o[4] = {lo.x, lo.y, hi.x, hi.y};
            *(short8*)(dst + (size_t)d * S_LEN + c8 * 8) = *(short8*)o;
        }
    }
}

// ---------------------------------------------------------------------------
// Flash attention, K-split internal: wave-groups 0-3 (ks=0) / 4-7 (ks=1) of a
// 512-thread block. Grid: 512 = (b*8+h)*32+qt. P stays in registers (R7
// permuted-K staging). Epilogue: f32 cross-group combine via LDS, direct
// bf16 ctx write. LDS 64KB. (R13 + hoisted addressing, kt unrolled x2)
// ---------------------------------------------------------------------------
__global__ __launch_bounds__(512, 4) void attn_kernel(
    const float* __restrict__ Q, const unsigned short* __restrict__ K16,
    const unsigned short* __restrict__ Vt,
    const float* __restrict__ risk_sigma, const float* __restrict__ risk_lambda,
    unsigned short* __restrict__ ctx)
{
    __shared__ unsigned short SH[32768];   // 64 KiB

    const int tid  = threadIdx.x;
    const int wave = tid >> 6;
    const int grp  = wave >> 2;            // K-split half
    const int wv   = wave & 3;             // wave within group
    const int lane = tid & 63;
    const int quad = lane >> 4;
    const int ln   = lane & 15;
    const int sw   = ln & 7;

    const int bid = blockIdx.x;            // (b*8+h)*32+qt
    const int qt  = bid & 31;
    const int h   = (bid >> 5) & 7;
    const int b   = bid >> 8;
    const int qbase = qt * 128;

    float sig = risk_sigma[b];
    sig = fminf(fmaxf(sig, 0.001f), 0.2f);
    const float sn   = (sig - 0.001f) * (1.0f / 0.199f);
    const float coef = risk_lambda[0] * 0.1f * sn;
    const float nc2 = -coef * (1.0f / 4096.0f) * (1.0f / 4096.0f) * 1.4426950408889634f;
    const float b1c = nc2, b4c = 4.0f * nc2, b9c = 9.0f * nc2;
    const float qscale = 0.125f * 1.4426950408889634f;

    const float* Qb = Q + (size_t)b * S_LEN * HTOT + (size_t)h * HD;
    const unsigned short* Kb = K16 + (size_t)b * S_LEN * HTOT + (size_t)h * HD;
    const unsigned short* Vb = Vt + ((size_t)(b * 8 + h) * 64) * S_LEN;

    const int rl  = lane >> 3;
    const int c8g = ((lane & 7) ^ rl) << 3;
    // permuted K source row for LDS dest row rr = wv*8+rl:
    // src = [r3 r2 r4 r1 r0] of rr's low 5 bits (R7 mapping, per group)
    const int ksrow = ((wv & 1) << 4) | (((rl >> 2) & 1) << 3)
                    | ((wv >> 1) << 2) | (rl & 3);

    const int kb0 = grp * 2048;

    // ---- hoisted incremental global prefetch pointers (advance per kt) ----
    const unsigned short* gk = Kb + (size_t)(kb0 + ksrow) * HTOT + c8g;
    const unsigned short* gv = Vb + (size_t)(wv * 8 + rl) * S_LEN + kb0 + c8g;

    // ---- hoisted LDS staging destinations (per buffer) ----
    unsigned short* ldK0 = SH + (grp * 2 + 0) * 8192 + wv * 512 + lane * 8;
    unsigned short* ldK1 = SH + (grp * 2 + 1) * 8192 + wv * 512 + lane * 8;

    auto dma2 = [&](int buf) {
        unsigned short* dk = buf ? ldK1 : ldK0;
        async16(gk,              dk);
        async16(gk + 32 * HTOT,  dk + 2048);
        async16(gv,              dk + 4096);
        async16(gv + 32 * S_LEN, dk + 6144);
    };

    dma2(0);
    gk += 64 * HTOT;
    gv += 64;

    // ---- hoisted LDS read bases (per buffer; jt/dt*1024 folds to imm) ----
    const unsigned short* base0 = SH + grp * 16384;
    const unsigned short* base1 = base0 + 8192;
    const int off0 = ln * 64 + ((quad ^ sw) << 3);
    const int off1 = ln * 64 + (((quad + 4) ^ sw) << 3);
    const unsigned short* KA0_0 = base0 + off0;
    const unsigned short* KA1_0 = base0 + off1;
    const unsigned short* KA0_1 = base1 + off0;
    const unsigned short* KA1_1 = base1 + off1;
    const unsigned short* VA0_0 = base0 + 4096 + off0;
    const unsigned short* VA1_0 = base0 + 4096 + off1;
    const unsigned short* VA0_1 = base1 + 4096 + off0;
    const unsigned short* VA1_1 = base1 + 4096 + off1;

    // Q fragments straight from global, qscale folded.
    short8 qf[2][2];
    {
        const float* qp0 = Qb + (size_t)(qbase + wv * 32 + ln) * HTOT + quad * 8;
        #pragma unroll
        for (int nt = 0; nt < 2; nt++) {
            const float* qp = qp0 + (size_t)(nt * 16) * HTOT;
            #pragma unroll
            for (int hf = 0; hf < 2; hf++) {
                float4 x = *(const float4*)(qp + hf * 32);
                float4 y = *(const float4*)(qp + hf * 32 + 4);
                unsigned o[4] = {pack_bf16(x.x * qscale, x.y * qscale),
                                 pack_bf16(x.z * qscale, x.w * qscale),
                                 pack_bf16(y.x * qscale, y.y * qscale),
                                 pack_bf16(y.z * qscale, y.w * qscale)};
                qf[nt][hf] = *(short8*)o;
            }
        }
    }
    __syncthreads();   // drains dma2(0)

    const short sone = (short)0x3F80;
    const short8 ones = {sone, sone, sone, sone, sone, sone, sone, sone};

    floatx4 Oacc[2][4], Lacc[2];
    #pragma unroll
    for (int nt = 0; nt < 2; nt++) {
        Lacc[nt] = (floatx4){0.f, 0.f, 0.f, 0.f};
        #pragma unroll
        for (int dt = 0; dt < 4; dt++) Oacc[nt][dt] = (floatx4){0.f, 0.f, 0.f, 0.f};
    }

    const int qa = qbase + wv * 32;
    // incremental distance base: dqq(kt) = (qa + ln - kbase) - quad*8
    float dqq = (float)(qa + ln - kb0) - (float)(quad * 8);

    auto body = [&](int cur, bool pref) {
        if (pref) {
            dma2(1 - cur);
            gk += 64 * HTOT;
            gv += 64;
        }
        const unsigned short* ka0 = cur ? KA0_1 : KA0_0;
        const unsigned short* ka1 = cur ? KA1_1 : KA1_0;
        const unsigned short* va0 = cur ? VA0_1 : VA0_0;
        const unsigned short* va1 = cur ? VA1_1 : VA1_0;

        unsigned pw[2][2][4];   // [nt][part][word] — PV A-fragments

        #pragma unroll
        for (int jt = 0; jt < 4; jt++) {
            short8 ak0 = *(const short8*)(ka0 + jt * 1024);
            short8 ak1 = *(const short8*)(ka1 + jt * 1024);
            const float jtoff = (float)((jt >> 1) * 32 + (jt & 1) * 4);
            #pragma unroll
            for (int nt = 0; nt < 2; nt++) {
                // rk[r] = nc2*(d0-r)^2 = t - 2r*(nc2*d0) + r^2*nc2 (R13 form)
                const float d0 = dqq + ((float)(nt * 16) - jtoff);
                const float s1 = nc2 * d0;
                const float t  = s1 * d0;
                floatx4 rk;
                rk[0] = t;
                rk[1] = __builtin_fmaf(-2.0f, s1, t) + b1c;
                rk[2] = __builtin_fmaf(-4.0f, s1, t) + b4c;
                rk[3] = __builtin_fmaf(-6.0f, s1, t) + b9c;
                floatx4 s = __builtin_amdgcn_mfma_f32_16x16x32_bf16(ak0, qf[nt][0], rk, 0, 0, 0);
                s = __builtin_amdgcn_mfma_f32_16x16x32_bf16(ak1, qf[nt][1], s, 0, 0, 0);
                float p0 = EXP2F(s[0]);
                float p1 = EXP2F(s[1]);
                float p2 = EXP2F(s[2]);
                float p3 = EXP2F(s[3]);
                pw[nt][jt >> 1][(jt & 1) * 2 + 0] = pack_trunc(p0, p1);
                pw[nt][jt >> 1][(jt & 1) * 2 + 1] = pack_trunc(p2, p3);
            }
        }

        __builtin_amdgcn_s_setprio(1);
        #pragma unroll
        for (int dt = 0; dt < 4; dt++) {
            short8 bv0 = *(const short8*)(va0 + dt * 1024);
            short8 bv1 = *(const short8*)(va1 + dt * 1024);
            #pragma unroll
            for (int nt = 0; nt < 2; nt++) {
                short8 pa0 = *(const short8*)&pw[nt][0][0];
                short8 pa1 = *(const short8*)&pw[nt][1][0];
                Oacc[nt][dt] = __builtin_amdgcn_mfma_f32_16x16x32_bf16(pa0, bv0, Oacc[nt][dt], 0, 0, 0);
                Oacc[nt][dt] = __builtin_amdgcn_mfma_f32_16x16x32_bf16(pa1, bv1, Oacc[nt][dt], 0, 0, 0);
            }
        }
        #pragma unroll
        for (int nt = 0; nt < 2; nt++) {
            short8 pa0 = *(const short8*)&pw[nt][0][0];
            short8 pa1 = *(const short8*)&pw[nt][1][0];
            Lacc[nt] = __builtin_amdgcn_mfma_f32_16x16x32_bf16(pa0, ones, Lacc[nt], 0, 0, 0);
            Lacc[nt] = __builtin_amdgcn_mfma_f32_16x16x32_bf16(pa1, ones, Lacc[nt], 0, 0, 0);
        }
        __builtin_amdgcn_s_setprio(0);
        __syncthreads();
        dqq -= 64.0f;
    };

    for (int kt2 = 0; kt2 < 16; ++kt2) {
        body(0, true);
        body(1, kt2 < 15);
    }

    // ---- epilogue: cross-group combine in LDS (f32), direct ctx write ----
    float* X   = (float*)SH;               // [128][68] f32
    float* Lsh = (float*)SH + 128 * 68;    // [2][128] f32

    if (ln == 0) {
        #pragma unroll
        for (int nt = 0; nt < 2; nt++)
            #pragma unroll
            for (int r = 0; r < 4; r++)
                Lsh[grp * 128 + wv * 32 + nt * 16 + quad * 4 + r] = Lacc[nt][r];
    }
    if (grp == 0) {
        #pragma unroll
        for (int nt = 0; nt < 2; nt++)
            #pragma unroll
            for (int dt = 0; dt < 4; dt++)
                #pragma unroll
                for (int r = 0; r < 4; r++)
                    X[(wv * 32 + nt * 16 + quad * 4 + r) * 68 + dt * 16 + ln] = Oacc[nt][dt][r];
    }
    __syncthreads();
    if (grp == 1) {
        #pragma unroll
        for (int nt = 0; nt < 2; nt++) {
            float inv[4];
            #pragma unroll
            for (int r = 0; r < 4; r++) {
                int row = wv * 32 + nt * 16 + quad * 4 + r;
                inv[r] = 1.0f / (Lsh[row] + Lsh[128 + row]);
            }
            #pragma unroll
            for (int dt = 0; dt < 4; dt++)
                #pragma unroll
                for (int r = 0; r < 4; r++) {
                    int row = wv * 32 + nt * 16 + quad * 4 + r;
                    float* p = &X[row * 68 + dt * 16 + ln];
                    *p = (*p + Oacc[nt][dt][r]) * inv[r];
                }
        }
    }
    __syncthreads();
    {
        const int q = tid >> 2;            // 128 rows, 4 threads/row
        const int c = tid & 3;             // 16-d chunk
        const float* xp = X + q * 68 + c * 16;
        float4 x0 = *(const float4*)(xp + 0);
        float4 x1 = *(const float4*)(xp + 4);
        float4 x2 = *(const float4*)(xp + 8);
        float4 x3 = *(const float4*)(xp + 12);
        unsigned o0[4] = {pack_bf16(x0.x, x0.y), pack_bf16(x0.z, x0.w),
                          pack_bf16(x1.x, x1.y), pack_bf16(x1.z, x1.w)};
        unsigned o1[4] = {pack_bf16(x2.x, x2.y), pack_bf16(x2.z, x2.w),
                          pack_bf16(x3.x, x3.y), pack_bf16(x3.z, x3.w)};
        unsigned short* cp = ctx + ((size_t)b * S_LEN + qbase + q) * HTOT + h * HD + c * 16;
        *(short8*)cp       = *(short8*)o0;
        *(short8*)(cp + 8) = *(short8*)o1;
    }
}

// ---------------------------------------------------------------------------
// Projection GEMM, all-bf16, DMA double-buffered staging. (R13 verbatim)
// ---------------------------------------------------------------------------
__global__ __launch_bounds__(256) void proj_kernel(
    const unsigned short* __restrict__ A,   // ctx bf16 [8192 x 512]
    const unsigned short* __restrict__ W16, // [512 x 512] bf16
    const float* __restrict__ bias,
    float* __restrict__ out)
{
    __shared__ unsigned short Ash[2][64 * 32];
    __shared__ unsigned short Bsh[2][128 * 32];
    const int tid = threadIdx.x;
    const int wave = tid >> 6, lane = tid & 63, quad = lane >> 4, ln = lane & 15;
    const int wr = wave >> 1, wc = wave & 1;
    const int m0 = blockIdx.y * 64;
    const int nb = blockIdx.x * 128;

    const int arow = (wave * 64 + lane) >> 2;
    const int ac   = (wave * 64 + lane) & 3;
    const int acs  = (ac ^ ((arow >> 1) & 3)) << 3;
    const int wrow0 = (wave * 64 + lane) >> 2;
    const int wc0   = (wave * 64 + lane) & 3;
    const int wcs0  = (wc0 ^ ((wrow0 >> 1) & 3)) << 3;
    const int wrow1 = wrow0 + 64;
    const int wcs1  = (wc0 ^ ((wrow1 >> 1) & 3)) << 3;

    auto dma = [&](int buf, int k0) {
        async16(A + (size_t)(m0 + arow) * 512 + k0 + acs,
                &Ash[buf][wave * 512 + lane * 8]);
        async16(W16 + (size_t)(nb + wrow0) * 512 + k0 + wcs0,
                &Bsh[buf][wave * 512 + lane * 8]);
        async16(W16 + (size_t)(nb + wrow1) * 512 + k0 + wcs1,
                &Bsh[buf][(wave + 4) * 512 + lane * 8]);
    };

    floatx4 acc[2][4];
    for (int i = 0; i < 2; i++)
        for (int j = 0; j < 4; j++) acc[i][j] = (floatx4){0.f, 0.f, 0.f, 0.f};

    dma(0, 0);
    for (int kt = 0; kt < 16; ++kt) {
        const int cur = kt & 1;
        __syncthreads();
        if (kt < 15) dma(1 - cur, (kt + 1) * 32);

        short8 af[2], bf[4];
        for (int i = 0; i < 2; i++) {
            int r = wr * 32 + i * 16 + ln;
            af[i] = *(const short8*)&Ash[cur][r * 32 + ((quad ^ ((r >> 1) & 3)) << 3)];
        }
        for (int j = 0; j < 4; j++) {
            int r = wc * 64 + j * 16 + ln;
            bf[j] = *(const short8*)&Bsh[cur][r * 32 + ((quad ^ ((r >> 1) & 3)) << 3)];
        }
        for (int i = 0; i < 2; i++)
            for (int j = 0; j < 4; j++)
                acc[i][j] = __builtin_amdgcn_mfma_f32_16x16x32_bf16(af[i], bf[j], acc[i][j], 0, 0, 0);
    }

    for (int i = 0; i < 2; i++) {
        int row = m0 + wr * 32 + i * 16 + quad * 4;
        for (int j = 0; j < 4; j++) {
            int col = nb + wc * 64 + j * 16 + ln;
            float bv = bias[col];
            #pragma unroll
            for (int r = 0; r < 4; r++)
                out[(size_t)(row + r) * 512 + col] = acc[i][j][r] + bv;
        }
    }
}

extern "C" void kernel_launch(void* const* d_in, const int* in_sizes, int n_in,
                              void* d_out, int out_size, void* d_ws, size_t ws_size,
                              hipStream_t stream) {
    const float* Q    = (const float*)d_in[0];
    const float* K    = (const float*)d_in[1];
    const float* V    = (const float*)d_in[2];
    const float* sig  = (const float*)d_in[3];
    const float* lam  = (const float*)d_in[4];
    const float* W    = (const float*)d_in[5];
    const float* bias = (const float*)d_in[6];

    unsigned short* K16 = (unsigned short*)d_ws;                          // 8 MB
    unsigned short* Vt  = (unsigned short*)((char*)d_ws + (8u << 20));    // 8 MB
    unsigned short* ctx = (unsigned short*)((char*)d_ws + (16u << 20));   // 8 MB
    unsigned short* W16 = (unsigned short*)((char*)d_ws + (24u << 20));   // 512 KB
    float* out = (float*)d_out;

    prep_kernel<<<dim3(3200), dim3(256), 0, stream>>>(K, K16, V, Vt, W, W16);
    attn_kernel<<<dim3(512), dim3(512), 0, stream>>>(Q, K16, Vt, sig, lam, ctx);
    proj_kernel<<<dim3(4, 128), dim3(256), 0, stream>>>(ctx, W16, bias, out);
}

// Round 9
// 189.758 us; speedup vs baseline: 2.3747x; 1.0031x over previous
//
#include <hip/hip_runtime.h>
#include <hip/hip_bf16.h>

// VolatilityModulatedAttention: B=2, S=4096, H=512, NH=8, HD=64
// Round 15: R14 (best: 190.3us) + XCD-locality block remap in attn only.
// Default dispatch round-robins consecutive bids over 8 XCDs, so the 32
// blocks sharing one (b,h)'s K16/Vt slice land on all 8 XCD L2s -> ~26MB of
// cross-XCD re-fetch (FETCH 73.8MB vs 48MB algorithmic). Remap bid ->
// (xcd=bid&7 owns bh=xcd*2+(slot>=32), qt=slot&31): each XCD's K16/Vt
// working set = 2MB, L2-resident. Bijective; no layout/numerics change.
// Everything else verbatim R14.

#define S_LEN 4096
#define HD 64
#define HTOT 512

typedef __attribute__((ext_vector_type(8))) short short8;
typedef __attribute__((ext_vector_type(4))) float floatx4;

#if __has_builtin(__builtin_amdgcn_exp2f)
#define EXP2F(x) __builtin_amdgcn_exp2f(x)
#else
#define EXP2F(x) exp2f(x)
#endif

__device__ __forceinline__ unsigned pack_bf16(float a, float b) {
    unsigned ua = __builtin_bit_cast(unsigned, a) + 0x8000u;
    unsigned ub = __builtin_bit_cast(unsigned, b) + 0x8000u;
    return __builtin_amdgcn_perm(ub, ua, 0x07060302u);
}

// truncation pack (no rounding adds). P only: O and L consume the same stored
// P, so the uniform truncation bias cancels in O/L. Validated R11-R14.
__device__ __forceinline__ unsigned pack_trunc(float a, float b) {
    return __builtin_amdgcn_perm(__builtin_bit_cast(unsigned, b),
                                 __builtin_bit_cast(unsigned, a), 0x07060302u);
}

__device__ __forceinline__ unsigned short f2bf(float x) {
    unsigned u = __builtin_bit_cast(unsigned, x) + 0x8000u;
    return (unsigned short)(u >> 16);
}

__device__ __forceinline__ void async16(const unsigned short* g, unsigned short* l) {
    __builtin_amdgcn_global_load_lds(
        (const __attribute__((address_space(1))) unsigned int*)g,
        (__attribute__((address_space(3))) unsigned int*)l, 16, 0, 0);
}

// ---------------------------------------------------------------------------
// Fused prepass. [0,2048): K fp32->bf16. [2048,3072): V per-head transpose
// Vt[B*8][64][4096]. [3072,3200): W fp32->bf16.  (R14 verbatim)
// ---------------------------------------------------------------------------
__global__ __launch_bounds__(256) void prep_kernel(
    const float* __restrict__ K, unsigned short* __restrict__ K16,
    const float* __restrict__ V, unsigned short* __restrict__ Vt,
    const float* __restrict__ W, unsigned short* __restrict__ W16)
{
    const int tid = threadIdx.x;
    if (blockIdx.x >= 3072) {
        size_t i = ((size_t)(blockIdx.x - 3072) * 256 + tid) * 8;
        float4 a = *(const float4*)(W + i);
        float4 b = *(const float4*)(W + i + 4);
        unsigned o[4] = {pack_bf16(a.x, a.y), pack_bf16(a.z, a.w),
                         pack_bf16(b.x, b.y), pack_bf16(b.z, b.w)};
        *(short8*)(W16 + i) = *(short8*)o;
    } else if (blockIdx.x < 2048) {
        size_t i = ((size_t)blockIdx.x * 256 + tid) * 8;
        float4 a = *(const float4*)(K + i);
        float4 b = *(const float4*)(K + i + 4);
        unsigned o[4] = {pack_bf16(a.x, a.y), pack_bf16(a.z, a.w),
                         pack_bf16(b.x, b.y), pack_bf16(b.z, b.w)};
        *(short8*)(K16 + i) = *(short8*)o;
    } else {
        __shared__ unsigned short T[64 * 66];   // [d][s]
        const int blk = blockIdx.x - 2048;
        const int st = blk & 63;
        const int bh = blk >> 6;
        const int b = bh >> 3, h = bh & 7;
        const float* src = V + ((size_t)b * S_LEN + st * 64) * HTOT + h * HD;
        for (int i = 0; i < 4; i++) {
            int idx = tid + i * 256;
            int s = idx >> 4, c4 = idx & 15;
            float4 v = *(const float4*)(src + (size_t)s * HTOT + c4 * 4);
            T[(c4 * 4 + 0) * 66 + s] = f2bf(v.x);
            T[(c4 * 4 + 1) * 66 + s] = f2bf(v.y);
            T[(c4 * 4 + 2) * 66 + s] = f2bf(v.z);
            T[(c4 * 4 + 3) * 66 + s] = f2bf(v.w);
        }
        __syncthreads();
        unsigned short* dst = Vt + ((size_t)bh * 64) * S_LEN + st * 64;
        for (int i = 0; i < 2; i++) {
            int idx = tid + i * 256;
            int d = idx >> 3, c8 = idx & 7;
            uint2 lo = *(const uint2*)&T[d * 66 + c8 * 8];
            uint2 hi = *(const uint2*)&T[d * 66 + c8 * 8 + 4];
            unsigned o[4] = {lo.x, lo.y, hi.x, hi.y};
            *(short8*)(dst + (size_t)d * S_LEN + c8 * 8) = *(short8*)o;
        }
    }
}

// ---------------------------------------------------------------------------
// Flash attention, K-split internal: wave-groups 0-3 (ks=0) / 4-7 (ks=1) of a
// 512-thread block. Grid: 512, XCD-remapped: xcd=bid&7 owns bh=xcd*2+(slot>=32).
// P stays in registers (R7 permuted-K staging). Epilogue: f32 cross-group
// combine via LDS, direct bf16 ctx write. LDS 64KB. (R14 + XCD remap)
// ---------------------------------------------------------------------------
__global__ __launch_bounds__(512, 4) void attn_kernel(
    const float* __restrict__ Q, const unsigned short* __restrict__ K16,
    const unsigned short* __restrict__ Vt,
    const float* __restrict__ risk_sigma, const float* __restrict__ risk_lambda,
    unsigned short* __restrict__ ctx)
{
    __shared__ unsigned short SH[32768];   // 64 KiB

    const int tid  = threadIdx.x;
    const int wave = tid >> 6;
    const int grp  = wave >> 2;            // K-split half
    const int wv   = wave & 3;             // wave within group
    const int lane = tid & 63;
    const int quad = lane >> 4;
    const int ln   = lane & 15;
    const int sw   = ln & 7;

    // XCD-locality remap: consecutive bids round-robin over 8 XCDs, so give
    // xcd = bid&7 a contiguous pair of bh groups; K16/Vt slices (2MB) become
    // L2-resident per XCD. Bijective on [0,512).
    const int xcd  = blockIdx.x & 7;
    const int slot = blockIdx.x >> 3;      // 0..63
    const int bh   = xcd * 2 + (slot >> 5);
    const int qt   = slot & 31;
    const int h    = bh & 7;
    const int b    = bh >> 3;
    const int qbase = qt * 128;

    float sig = risk_sigma[b];
    sig = fminf(fmaxf(sig, 0.001f), 0.2f);
    const float sn   = (sig - 0.001f) * (1.0f / 0.199f);
    const float coef = risk_lambda[0] * 0.1f * sn;
    const float nc2 = -coef * (1.0f / 4096.0f) * (1.0f / 4096.0f) * 1.4426950408889634f;
    const float b1c = nc2, b4c = 4.0f * nc2, b9c = 9.0f * nc2;
    const float qscale = 0.125f * 1.4426950408889634f;

    const float* Qb = Q + (size_t)b * S_LEN * HTOT + (size_t)h * HD;
    const unsigned short* Kb = K16 + (size_t)b * S_LEN * HTOT + (size_t)h * HD;
    const unsigned short* Vb = Vt + ((size_t)(b * 8 + h) * 64) * S_LEN;

    const int rl  = lane >> 3;
    const int c8g = ((lane & 7) ^ rl) << 3;
    // permuted K source row for LDS dest row rr = wv*8+rl:
    // src = [r3 r2 r4 r1 r0] of rr's low 5 bits (R7 mapping, per group)
    const int ksrow = ((wv & 1) << 4) | (((rl >> 2) & 1) << 3)
                    | ((wv >> 1) << 2) | (rl & 3);

    const int kb0 = grp * 2048;

    // ---- hoisted incremental global prefetch pointers (advance per kt) ----
    const unsigned short* gk = Kb + (size_t)(kb0 + ksrow) * HTOT + c8g;
    const unsigned short* gv = Vb + (size_t)(wv * 8 + rl) * S_LEN + kb0 + c8g;

    // ---- hoisted LDS staging destinations (per buffer) ----
    unsigned short* ldK0 = SH + (grp * 2 + 0) * 8192 + wv * 512 + lane * 8;
    unsigned short* ldK1 = SH + (grp * 2 + 1) * 8192 + wv * 512 + lane * 8;

    auto dma2 = [&](int buf) {
        unsigned short* dk = buf ? ldK1 : ldK0;
        async16(gk,              dk);
        async16(gk + 32 * HTOT,  dk + 2048);
        async16(gv,              dk + 4096);
        async16(gv + 32 * S_LEN, dk + 6144);
    };

    dma2(0);
    gk += 64 * HTOT;
    gv += 64;

    // ---- hoisted LDS read bases (per buffer; jt/dt*1024 folds to imm) ----
    const unsigned short* base0 = SH + grp * 16384;
    const unsigned short* base1 = base0 + 8192;
    const int off0 = ln * 64 + ((quad ^ sw) << 3);
    const int off1 = ln * 64 + (((quad + 4) ^ sw) << 3);
    const unsigned short* KA0_0 = base0 + off0;
    const unsigned short* KA1_0 = base0 + off1;
    const unsigned short* KA0_1 = base1 + off0;
    const unsigned short* KA1_1 = base1 + off1;
    const unsigned short* VA0_0 = base0 + 4096 + off0;
    const unsigned short* VA1_0 = base0 + 4096 + off1;
    const unsigned short* VA0_1 = base1 + 4096 + off0;
    const unsigned short* VA1_1 = base1 + 4096 + off1;

    // Q fragments straight from global, qscale folded.
    short8 qf[2][2];
    {
        const float* qp0 = Qb + (size_t)(qbase + wv * 32 + ln) * HTOT + quad * 8;
        #pragma unroll
        for (int nt = 0; nt < 2; nt++) {
            const float* qp = qp0 + (size_t)(nt * 16) * HTOT;
            #pragma unroll
            for (int hf = 0; hf < 2; hf++) {
                float4 x = *(const float4*)(qp + hf * 32);
                float4 y = *(const float4*)(qp + hf * 32 + 4);
                unsigned o[4] = {pack_bf16(x.x * qscale, x.y * qscale),
                                 pack_bf16(x.z * qscale, x.w * qscale),
                                 pack_bf16(y.x * qscale, y.y * qscale),
                                 pack_bf16(y.z * qscale, y.w * qscale)};
                qf[nt][hf] = *(short8*)o;
            }
        }
    }
    __syncthreads();   // drains dma2(0)

    const short sone = (short)0x3F80;
    const short8 ones = {sone, sone, sone, sone, sone, sone, sone, sone};

    floatx4 Oacc[2][4], Lacc[2];
    #pragma unroll
    for (int nt = 0; nt < 2; nt++) {
        Lacc[nt] = (floatx4){0.f, 0.f, 0.f, 0.f};
        #pragma unroll
        for (int dt = 0; dt < 4; dt++) Oacc[nt][dt] = (floatx4){0.f, 0.f, 0.f, 0.f};
    }

    const int qa = qbase + wv * 32;
    // incremental distance base: dqq(kt) = (qa + ln - kbase) - quad*8
    float dqq = (float)(qa + ln - kb0) - (float)(quad * 8);

    auto body = [&](int cur, bool pref) {
        if (pref) {
            dma2(1 - cur);
            gk += 64 * HTOT;
            gv += 64;
        }
        const unsigned short* ka0 = cur ? KA0_1 : KA0_0;
        const unsigned short* ka1 = cur ? KA1_1 : KA1_0;
        const unsigned short* va0 = cur ? VA0_1 : VA0_0;
        const unsigned short* va1 = cur ? VA1_1 : VA1_0;

        unsigned pw[2][2][4];   // [nt][part][word] — PV A-fragments

        #pragma unroll
        for (int jt = 0; jt < 4; jt++) {
            short8 ak0 = *(const short8*)(ka0 + jt * 1024);
            short8 ak1 = *(const short8*)(ka1 + jt * 1024);
            const float jtoff = (float)((jt >> 1) * 32 + (jt & 1) * 4);
            #pragma unroll
            for (int nt = 0; nt < 2; nt++) {
                // rk[r] = nc2*(d0-r)^2 = t - 2r*(nc2*d0) + r^2*nc2 (R13 form)
                const float d0 = dqq + ((float)(nt * 16) - jtoff);
                const float s1 = nc2 * d0;
                const float t  = s1 * d0;
                floatx4 rk;
                rk[0] = t;
                rk[1] = __builtin_fmaf(-2.0f, s1, t) + b1c;
                rk[2] = __builtin_fmaf(-4.0f, s1, t) + b4c;
                rk[3] = __builtin_fmaf(-6.0f, s1, t) + b9c;
                floatx4 s = __builtin_amdgcn_mfma_f32_16x16x32_bf16(ak0, qf[nt][0], rk, 0, 0, 0);
                s = __builtin_amdgcn_mfma_f32_16x16x32_bf16(ak1, qf[nt][1], s, 0, 0, 0);
                float p0 = EXP2F(s[0]);
                float p1 = EXP2F(s[1]);
                float p2 = EXP2F(s[2]);
                float p3 = EXP2F(s[3]);
                pw[nt][jt >> 1][(jt & 1) * 2 + 0] = pack_trunc(p0, p1);
                pw[nt][jt >> 1][(jt & 1) * 2 + 1] = pack_trunc(p2, p3);
            }
        }

        __builtin_amdgcn_s_setprio(1);
        #pragma unroll
        for (int dt = 0; dt < 4; dt++) {
            short8 bv0 = *(const short8*)(va0 + dt * 1024);
            short8 bv1 = *(const short8*)(va1 + dt * 1024);
            #pragma unroll
            for (int nt = 0; nt < 2; nt++) {
                short8 pa0 = *(const short8*)&pw[nt][0][0];
                short8 pa1 = *(const short8*)&pw[nt][1][0];
                Oacc[nt][dt] = __builtin_amdgcn_mfma_f32_16x16x32_bf16(pa0, bv0, Oacc[nt][dt], 0, 0, 0);
                Oacc[nt][dt] = __builtin_amdgcn_mfma_f32_16x16x32_bf16(pa1, bv1, Oacc[nt][dt], 0, 0, 0);
            }
        }
        #pragma unroll
        for (int nt = 0; nt < 2; nt++) {
            short8 pa0 = *(const short8*)&pw[nt][0][0];
            short8 pa1 = *(const short8*)&pw[nt][1][0];
            Lacc[nt] = __builtin_amdgcn_mfma_f32_16x16x32_bf16(pa0, ones, Lacc[nt], 0, 0, 0);
            Lacc[nt] = __builtin_amdgcn_mfma_f32_16x16x32_bf16(pa1, ones, Lacc[nt], 0, 0, 0);
        }
        __builtin_amdgcn_s_setprio(0);
        __syncthreads();
        dqq -= 64.0f;
    };

    for (int kt2 = 0; kt2 < 16; ++kt2) {
        body(0, true);
        body(1, kt2 < 15);
    }

    // ---- epilogue: cross-group combine in LDS (f32), direct ctx write ----
    float* X   = (float*)SH;               // [128][68] f32
    float* Lsh = (float*)SH + 128 * 68;    // [2][128] f32

    if (ln == 0) {
        #pragma unroll
        for (int nt = 0; nt < 2; nt++)
            #pragma unroll
            for (int r = 0; r < 4; r++)
                Lsh[grp * 128 + wv * 32 + nt * 16 + quad * 4 + r] = Lacc[nt][r];
    }
    if (grp == 0) {
        #pragma unroll
        for (int nt = 0; nt < 2; nt++)
            #pragma unroll
            for (int dt = 0; dt < 4; dt++)
                #pragma unroll
                for (int r = 0; r < 4; r++)
                    X[(wv * 32 + nt * 16 + quad * 4 + r) * 68 + dt * 16 + ln] = Oacc[nt][dt][r];
    }
    __syncthreads();
    if (grp == 1) {
        #pragma unroll
        for (int nt = 0; nt < 2; nt++) {
            float inv[4];
            #pragma unroll
            for (int r = 0; r < 4; r++) {
                int row = wv * 32 + nt * 16 + quad * 4 + r;
                inv[r] = 1.0f / (Lsh[row] + Lsh[128 + row]);
            }
            #pragma unroll
            for (int dt = 0; dt < 4; dt++)
                #pragma unroll
                for (int r = 0; r < 4; r++) {
                    int row = wv * 32 + nt * 16 + quad * 4 + r;
                    float* p = &X[row * 68 + dt * 16 + ln];
                    *p = (*p + Oacc[nt][dt][r]) * inv[r];
                }
        }
    }
    __syncthreads();
    {
        const int q = tid >> 2;            // 128 rows, 4 threads/row
        const int c = tid & 3;             // 16-d chunk
        const float* xp = X + q * 68 + c * 16;
        float4 x0 = *(const float4*)(xp + 0);
        float4 x1 = *(const float4*)(xp + 4);
        float4 x2 = *(const float4*)(xp + 8);
        float4 x3 = *(const float4*)(xp + 12);
        unsigned o0[4] = {pack_bf16(x0.x, x0.y), pack_bf16(x0.z, x0.w),
                          pack_bf16(x1.x, x1.y), pack_bf16(x1.z, x1.w)};
        unsigned o1[4] = {pack_bf16(x2.x, x2.y), pack_bf16(x2.z, x2.w),
                          pack_bf16(x3.x, x3.y), pack_bf16(x3.z, x3.w)};
        unsigned short* cp = ctx + ((size_t)b * S_LEN + qbase + q) * HTOT + h * HD + c * 16;
        *(short8*)cp       = *(short8*)o0;
        *(short8*)(cp + 8) = *(short8*)o1;
    }
}

// ---------------------------------------------------------------------------
// Projection GEMM, all-bf16, DMA double-buffered staging. (R14 verbatim)
// ---------------------------------------------------------------------------
__global__ __launch_bounds__(256) void proj_kernel(
    const unsigned short* __restrict__ A,   // ctx bf16 [8192 x 512]
    const unsigned short* __restrict__ W16, // [512 x 512] bf16
    const float* __restrict__ bias,
    float* __restrict__ out)
{
    __shared__ unsigned short Ash[2][64 * 32];
    __shared__ unsigned short Bsh[2][128 * 32];
    const int tid = threadIdx.x;
    const int wave = tid >> 6, lane = tid & 63, quad = lane >> 4, ln = lane & 15;
    const int wr = wave >> 1, wc = wave & 1;
    const int m0 = blockIdx.y * 64;
    const int nb = blockIdx.x * 128;

    const int arow = (wave * 64 + lane) >> 2;
    const int ac   = (wave * 64 + lane) & 3;
    const int acs  = (ac ^ ((arow >> 1) & 3)) << 3;
    const int wrow0 = (wave * 64 + lane) >> 2;
    const int wc0   = (wave * 64 + lane) & 3;
    const int wcs0  = (wc0 ^ ((wrow0 >> 1) & 3)) << 3;
    const int wrow1 = wrow0 + 64;
    const int wcs1  = (wc0 ^ ((wrow1 >> 1) & 3)) << 3;

    auto dma = [&](int buf, int k0) {
        async16(A + (size_t)(m0 + arow) * 512 + k0 + acs,
                &Ash[buf][wave * 512 + lane * 8]);
        async16(W16 + (size_t)(nb + wrow0) * 512 + k0 + wcs0,
                &Bsh[buf][wave * 512 + lane * 8]);
        async16(W16 + (size_t)(nb + wrow1) * 512 + k0 + wcs1,
                &Bsh[buf][(wave + 4) * 512 + lane * 8]);
    };

    floatx4 acc[2][4];
    for (int i = 0; i < 2; i++)
        for (int j = 0; j < 4; j++) acc[i][j] = (floatx4){0.f, 0.f, 0.f, 0.f};

    dma(0, 0);
    for (int kt = 0; kt < 16; ++kt) {
        const int cur = kt & 1;
        __syncthreads();
        if (kt < 15) dma(1 - cur, (kt + 1) * 32);

        short8 af[2], bf[4];
        for (int i = 0; i < 2; i++) {
            int r = wr * 32 + i * 16 + ln;
            af[i] = *(const short8*)&Ash[cur][r * 32 + ((quad ^ ((r >> 1) & 3)) << 3)];
        }
        for (int j = 0; j < 4; j++) {
            int r = wc * 64 + j * 16 + ln;
            bf[j] = *(const short8*)&Bsh[cur][r * 32 + ((quad ^ ((r >> 1) & 3)) << 3)];
        }
        for (int i = 0; i < 2; i++)
            for (int j = 0; j < 4; j++)
                acc[i][j] = __builtin_amdgcn_mfma_f32_16x16x32_bf16(af[i], bf[j], acc[i][j], 0, 0, 0);
    }

    for (int i = 0; i < 2; i++) {
        int row = m0 + wr * 32 + i * 16 + quad * 4;
        for (int j = 0; j < 4; j++) {
            int col = nb + wc * 64 + j * 16 + ln;
            float bv = bias[col];
            #pragma unroll
            for (int r = 0; r < 4; r++)
                out[(size_t)(row + r) * 512 + col] = acc[i][j][r] + bv;
        }
    }
}

extern "C" void kernel_launch(void* const* d_in, const int* in_sizes, int n_in,
                              void* d_out, int out_size, void* d_ws, size_t ws_size,
                              hipStream_t stream) {
    const float* Q    = (const float*)d_in[0];
    const float* K    = (const float*)d_in[1];
    const float* V    = (const float*)d_in[2];
    const float* sig  = (const float*)d_in[3];
    const float* lam  = (const float*)d_in[4];
    const float* W    = (const float*)d_in[5];
    const float* bias = (const float*)d_in[6];

    unsigned short* K16 = (unsigned short*)d_ws;                          // 8 MB
    unsigned short* Vt  = (unsigned short*)((char*)d_ws + (8u << 20));    // 8 MB
    unsigned short* ctx = (unsigned short*)((char*)d_ws + (16u << 20));   // 8 MB
    unsigned short* W16 = (unsigned short*)((char*)d_ws + (24u << 20));   // 512 KB
    float* out = (float*)d_out;

    prep_kernel<<<dim3(3200), dim3(256), 0, stream>>>(K, K16, V, Vt, W, W16);
    attn_kernel<<<dim3(512), dim3(512), 0, stream>>>(Q, K16, Vt, sig, lam, ctx);
    proj_kernel<<<dim3(4, 128), dim3(256), 0, stream>>>(ctx, W16, bias, out);
}